// Round 5
// baseline (525.278 us; speedup 1.0000x reference)
//
#include <hip/hip_runtime.h>

typedef unsigned short u16;
typedef unsigned int   u32;
typedef short bf16x8 __attribute__((ext_vector_type(8)));
typedef float f32x4  __attribute__((ext_vector_type(4)));

#define MFMA16(a,b,c) __builtin_amdgcn_mfma_f32_16x16x32_bf16((a),(b),(c),0,0,0)

// ---------- bf16 helpers (storage = u16, compute = f32) ----------
__device__ __forceinline__ float bf2f(u32 u){ union{u32 i; float f;} v; v.i = u<<16; return v.f; }
__device__ __forceinline__ u16 f2bf(float f){
  union{float f; u32 i;} v; v.f=f; u32 i=v.i;
  return (u16)((i + 0x7fffu + ((i>>16)&1u)) >> 16);   // round-nearest-even
}
__device__ __forceinline__ u32 pk2(float a, float b){ return (u32)f2bf(a) | ((u32)f2bf(b)<<16); }
__device__ __forceinline__ float geluf(float x){ return 0.5f*x*(1.f + erff(x*0.7071067811865475f)); }

// ---------- fused prep: all 6 weight transposes + grid_idx/histogram ----------
__global__ void k_prep(const float* __restrict__ wq, u16* __restrict__ wqT,
                       const float* __restrict__ wkv, u16* __restrict__ wkvT,
                       const float* __restrict__ wproj, u16* __restrict__ wprojT,
                       const float* __restrict__ fc1w, u16* __restrict__ fc1T,
                       const float* __restrict__ fc2w, u16* __restrict__ fc2T,
                       const float* __restrict__ srw, u16* __restrict__ srwT,
                       const float* __restrict__ loc, const int* __restrict__ iagg,
                       int* __restrict__ idx_hw, int* __restrict__ cnt_all){
  int t = blockIdx.x*256 + threadIdx.x;
  if(t < 458752){
    const float* w; u16* wt; int li, Nsh, K;
    if(t < 16384){ w=wq; wt=wqT; li=t; Nsh=7; K=128; }
    else if(t < 49152){ w=wkv; wt=wkvT; li=t-16384; Nsh=8; K=128; }
    else if(t < 65536){ w=wproj; wt=wprojT; li=t-49152; Nsh=7; K=128; }
    else if(t < 131072){ w=fc1w; wt=fc1T; li=t-65536; Nsh=9; K=128; }
    else if(t < 196608){ w=fc2w; wt=fc2T; li=t-131072; Nsh=7; K=512; }
    else { w=srw; wt=srwT; li=t-196608; Nsh=7; K=2048; }
    int k = li >> Nsh, n = li & ((1<<Nsh)-1);
    wt[(size_t)n*K + k] = f2bf(w[li]);
  } else {
    int tid = t - 458752;          // 0..131071
    int b = tid >> 14;
    float lx = loc[(size_t)tid*2];
    float ly = loc[(size_t)tid*2+1];
    float tx = (fminf(fmaxf(lx,-1.f),1.f)+1.f)*0.5f;
    float ty = (fminf(fmaxf(ly,-1.f),1.f)+1.f)*0.5f;
    int xi = (int)rintf(tx*63.f);   // round-half-even, matches jnp.round
    int yi = (int)rintf(ty*63.f);
    int cell = yi*64 + xi;
    idx_hw[tid] = cell;
    atomicAdd(&cnt_all[b*4096 + cell], 1);
    atomicAdd(&cnt_all[(8+b)*4096 + iagg[tid]], 1);
  }
}

// ---------- LayerNorm, register-resident: 4 threads per row, 2 shuffle rounds ----------
// Each thread owns a 32-float quarter (8 float4 in VGPRs); quad-local xor-1/xor-2
// combine gives full-row sum/sumsq with no long shuffle chains and no reload.
__device__ __forceinline__ void ln_row_quarter(const float* __restrict__ in, u16* __restrict__ outp,
    const float* __restrict__ g, const float* __restrict__ bt, int part){
  const float4* src = (const float4*)(in + part*32);
  float4 v[8];
  #pragma unroll
  for(int j=0;j<8;j++) v[j] = src[j];
  float s = 0.f, ss = 0.f;
  #pragma unroll
  for(int j=0;j<8;j++){
    s  += v[j].x + v[j].y + v[j].z + v[j].w;
    ss += v[j].x*v[j].x + v[j].y*v[j].y + v[j].z*v[j].z + v[j].w*v[j].w;
  }
  s  += __shfl_xor(s,1,64);  ss += __shfl_xor(ss,1,64);
  s  += __shfl_xor(s,2,64);  ss += __shfl_xor(ss,2,64);
  float mean = s*(1.f/128.f);
  float rstd = rsqrtf(ss*(1.f/128.f) - mean*mean + 1e-5f);
  const float4* gp = (const float4*)(g + part*32);
  const float4* bp = (const float4*)(bt + part*32);
  u32 o[16];
  #pragma unroll
  for(int j=0;j<8;j++){
    float4 gg = gp[j], bb = bp[j];
    o[2*j]   = pk2((v[j].x-mean)*rstd*gg.x + bb.x, (v[j].y-mean)*rstd*gg.y + bb.y);
    o[2*j+1] = pk2((v[j].z-mean)*rstd*gg.z + bb.z, (v[j].w-mean)*rstd*gg.w + bb.w);
  }
  int4* dst = (int4*)(outp + part*32);
  #pragma unroll
  for(int j=0;j<4;j++) dst[j] = ((const int4*)o)[j];
}

// two f32 sources fused: rows [0,32768) -> (in0,out0), [32768,163840) -> (in1,out1)
__global__ __launch_bounds__(256) void k_ln_x2(const float* __restrict__ in0, u16* __restrict__ out0,
    const float* __restrict__ in1, u16* __restrict__ out1,
    const float* __restrict__ g, const float* __restrict__ bt){
  int t = blockIdx.x*256 + threadIdx.x;
  int row = t >> 2, part = t & 3;
  const float* in; u16* outp;
  if(row < 32768){ in = in0 + (size_t)row*128; outp = out0 + (size_t)row*128; }
  else { int r2 = row - 32768; in = in1 + (size_t)r2*128; outp = out1 + (size_t)r2*128; }
  ln_row_quarter(in, outp, g, bt, part);
}

__global__ __launch_bounds__(256) void k_ln_f(const float* __restrict__ in, u16* __restrict__ outp,
    const float* __restrict__ g, const float* __restrict__ bt, int rows){
  int t = blockIdx.x*256 + threadIdx.x;
  int row = t >> 2, part = t & 3;
  if(row >= rows) return;
  ln_row_quarter(in + (size_t)row*128, outp + (size_t)row*128, g, bt, part);
}

// ---------- LN over sum of 4 split-K partials + conv bias (register-resident) ----------
__global__ __launch_bounds__(256) void k_ln_sr(const float* __restrict__ part, const float* __restrict__ srb,
    const float* __restrict__ g, const float* __restrict__ bt, u16* __restrict__ outp){
  int t = blockIdx.x*256 + threadIdx.x;     // 2048 rows * 4 = 8192 threads
  int row = t >> 2, pq = t & 3;
  const float4* p0 = (const float4*)(part +            (size_t)row*128 + pq*32);
  const float4* p1 = (const float4*)(part + 262144  +  (size_t)row*128 + pq*32);
  const float4* p2 = (const float4*)(part + 524288  +  (size_t)row*128 + pq*32);
  const float4* p3 = (const float4*)(part + 786432  +  (size_t)row*128 + pq*32);
  const float4* sb = (const float4*)(srb + pq*32);
  float4 v[8];
  float s = 0.f, ss = 0.f;
  #pragma unroll
  for(int j=0;j<8;j++){
    float4 a = p0[j], b2 = p1[j], c = p2[j], d = p3[j], e = sb[j];
    v[j].x = a.x+b2.x+c.x+d.x+e.x;
    v[j].y = a.y+b2.y+c.y+d.y+e.y;
    v[j].z = a.z+b2.z+c.z+d.z+e.z;
    v[j].w = a.w+b2.w+c.w+d.w+e.w;
    s  += v[j].x + v[j].y + v[j].z + v[j].w;
    ss += v[j].x*v[j].x + v[j].y*v[j].y + v[j].z*v[j].z + v[j].w*v[j].w;
  }
  s  += __shfl_xor(s,1,64);  ss += __shfl_xor(ss,1,64);
  s  += __shfl_xor(s,2,64);  ss += __shfl_xor(ss,2,64);
  float mean = s*(1.f/128.f);
  float rstd = rsqrtf(ss*(1.f/128.f) - mean*mean + 1e-5f);
  const float4* gp = (const float4*)(g + pq*32);
  const float4* bp = (const float4*)(bt + pq*32);
  u32 o[16];
  #pragma unroll
  for(int j=0;j<8;j++){
    float4 gg = gp[j], bb = bp[j];
    o[2*j]   = pk2((v[j].x-mean)*rstd*gg.x + bb.x, (v[j].y-mean)*rstd*gg.y + bb.y);
    o[2*j+1] = pk2((v[j].z-mean)*rstd*gg.z + bb.z, (v[j].w-mean)*rstd*gg.w + bb.w);
  }
  int4* dst = (int4*)(outp + (size_t)row*128 + pq*32);
  #pragma unroll
  for(int j=0;j<4;j++) dst[j] = ((const int4*)o)[j];
}

// ---------- exclusive scan of 4096 counts per (b,grouping); 16 blocks ----------
__global__ __launch_bounds__(1024) void k_scan(const int* __restrict__ cnt_all,
    int* __restrict__ offs_all, int* __restrict__ cur_all){
  int g = blockIdx.x;
  const int* src = cnt_all + g*4096;
  int* offs = offs_all + g*4097;
  int* cur  = cur_all  + g*4096;
  __shared__ int part[1024];
  int t = threadIdx.x;
  int v0=src[4*t], v1=src[4*t+1], v2=src[4*t+2], v3=src[4*t+3];
  int s = v0+v1+v2+v3;
  part[t] = s; __syncthreads();
  for(int off=1; off<1024; off<<=1){
    int x = (t>=off) ? part[t-off] : 0;
    __syncthreads();
    part[t] += x;
    __syncthreads();
  }
  int base = part[t] - s;
  offs[4*t]   = base;          cur[4*t]   = base;
  offs[4*t+1] = base+v0;       cur[4*t+1] = base+v0;
  offs[4*t+2] = base+v0+v1;    cur[4*t+2] = base+v0+v1;
  offs[4*t+3] = base+v0+v1+v2; cur[4*t+3] = base+v0+v1+v2;
  if(t==1023) offs[4096] = base+s;
}

// ---------- fill sorted point lists ----------
__global__ void k_fill(const int* __restrict__ idx_hw, const int* __restrict__ iagg,
                       int* __restrict__ cur_all, int* __restrict__ list_all){
  int tid = blockIdx.x*256 + threadIdx.x;
  int b = tid >> 14, i = tid & 16383;
  int cell = idx_hw[tid];
  int p = atomicAdd(&cur_all[b*4096 + cell], 1);
  list_all[(b<<14) + p] = i;
  int tok = iagg[tid];
  p = atomicAdd(&cur_all[(8+b)*4096 + tok], 1);
  list_all[((8+b)<<14) + p] = i;
}

// ---------- token2map for [xsn | conf]: 4 waves per block, one cell per wave ----------
__global__ __launch_bounds__(256) void k_tmap(const u16* __restrict__ xsn, const float* __restrict__ confs,
    const int* __restrict__ iaggs, const int* __restrict__ offs_all, const int* __restrict__ list_all,
    u16* __restrict__ xs_map, float* __restrict__ conf_p){
  int gcell = blockIdx.x*4 + (threadIdx.x >> 6);
  int b = gcell >> 12, cell = gcell & 4095;
  int lane = threadIdx.x & 63;
  int st = offs_all[b*4097 + cell], en = offs_all[b*4097 + cell + 1];
  float a0=0.f, a1=0.f, cf=0.f;
  for(int p=st;p<en;p++){
    int i = list_all[(b<<14)+p];
    int src = iaggs[(b<<14)+i];
    u32 u = ((const u32*)(xsn + ((size_t)(b<<14)+src)*128))[lane];
    a0 += bf2f(u & 0xffffu);
    a1 += bf2f(u >> 16);
    cf += confs[(b<<14)+src];
  }
  float inv = 1.f/fmaxf((float)(en-st), 1.f);
  ((u32*)(xs_map + ((size_t)(b<<12)+cell)*128))[lane] = pk2(a0*inv, a1*inv);
  if(lane==0){
    int ci = ((cell>>8)<<4) + ((cell&63)>>2);   // (yi/4)*16 + (xi/4)
    atomicAdd(&conf_p[b*256 + ci], cf*inv*(1.f/16.f));
  }
}

// ---------- sr-conv GEMM, split-K=4, im2col fused into A staging ----------
__global__ __launch_bounds__(256) void k_gemm_sr(const u16* __restrict__ xs_map, const u16* __restrict__ Wt,
    float* __restrict__ part){
  __shared__ __attribute__((aligned(16))) u16 lA[128*80];
  __shared__ __attribute__((aligned(16))) u16 lB[128*80];
  int m0 = blockIdx.x*128;
  int kbase = blockIdx.y*512;
  int tid = threadIdx.x, lane = tid & 63, wv = tid >> 6;
  int wm = (wv>>1)*64, wn = (wv&1)*64;
  int l16 = lane & 15, q4 = lane >> 4;
  f32x4 acc[4][4];
  for(int i=0;i<4;i++) for(int j=0;j<4;j++) acc[i][j] = (f32x4){0.f,0.f,0.f,0.f};
  for(int k0=kbase; k0<kbase+512; k0+=64){
    __syncthreads();
    for(int s=0;s<4;s++){
      int c = tid + s*256;
      int row = c >> 3, ko = (c & 7)*8;
      int m = m0 + row, k = k0 + ko;
      int b = m >> 8, oc = m & 255;
      int oy = oc >> 4, ox = oc & 15;
      int pos = k >> 7, ch = k & 127;
      int r = pos >> 2, ssp = pos & 3;
      int gy = oy*4 + r, gx = ox*4 + ssp;
      *(int4*)(lA + row*80 + ko) =
          *(const int4*)(xs_map + ((size_t)(b*4096) + gy*64 + gx)*128 + ch);
      *(int4*)(lB + row*80 + ko) = *(const int4*)(Wt + (size_t)row*2048 + k);
    }
    __syncthreads();
    for(int kk=0;kk<64;kk+=32){
      bf16x8 af[4], bfr[4];
      for(int i=0;i<4;i++) af[i]  = *(const bf16x8*)(lA + (wm + i*16 + l16)*80 + kk + q4*8);
      for(int j=0;j<4;j++) bfr[j] = *(const bf16x8*)(lB + (wn + j*16 + l16)*80 + kk + q4*8);
      for(int i=0;i<4;i++)
        for(int j=0;j<4;j++)
          acc[i][j] = MFMA16(af[i], bfr[j], acc[i][j]);
    }
  }
  float* outp = part + (size_t)blockIdx.y*262144;
  for(int i=0;i<4;i++) for(int j=0;j<4;j++){
    int col = wn + j*16 + l16;
    for(int r=0;r<4;r++){
      int row = m0 + wm + i*16 + q4*4 + r;
      outp[(size_t)row*128 + col] = acc[i][j][r];
    }
  }
}

// ---------- bf16 MFMA GEMM: out[M,N] = A[M,K] @ Wt[N,K]^T (+f32 bias)(+f32 res) ----------
__global__ __launch_bounds__(256) void k_gemm(const u16* __restrict__ Ag, const u16* __restrict__ Wt,
    const float* __restrict__ bias, const float* __restrict__ resf,
    u16* __restrict__ outb, float* __restrict__ outf, int M, int N, int K){
  __shared__ __attribute__((aligned(16))) u16 lA[128*80];
  __shared__ __attribute__((aligned(16))) u16 lB[128*80];
  int m0 = blockIdx.x*128, n0 = blockIdx.y*128;
  int tid = threadIdx.x, lane = tid & 63, wv = tid >> 6;
  int wm = (wv>>1)*64, wn = (wv&1)*64;
  int l16 = lane & 15, q4 = lane >> 4;
  f32x4 acc[4][4];
  for(int i=0;i<4;i++) for(int j=0;j<4;j++) acc[i][j] = (f32x4){0.f,0.f,0.f,0.f};
  for(int k0=0;k0<K;k0+=64){
    __syncthreads();
    for(int s=0;s<4;s++){
      int c = tid + s*256;
      int row = c >> 3, ko = (c & 7)*8;
      *(int4*)(lA + row*80 + ko) = *(const int4*)(Ag + (size_t)(m0+row)*K + k0 + ko);
      *(int4*)(lB + row*80 + ko) = *(const int4*)(Wt + (size_t)(n0+row)*K + k0 + ko);
    }
    __syncthreads();
    for(int kk=0;kk<64;kk+=32){
      bf16x8 af[4], bfr[4];
      for(int i=0;i<4;i++) af[i]  = *(const bf16x8*)(lA + (wm + i*16 + l16)*80 + kk + q4*8);
      for(int j=0;j<4;j++) bfr[j] = *(const bf16x8*)(lB + (wn + j*16 + l16)*80 + kk + q4*8);
      for(int i=0;i<4;i++)
        for(int j=0;j<4;j++)
          acc[i][j] = MFMA16(af[i], bfr[j], acc[i][j]);
    }
  }
  for(int i=0;i<4;i++) for(int j=0;j<4;j++){
    int col = n0 + wn + j*16 + l16;
    float bv = bias ? bias[col] : 0.f;
    for(int r=0;r<4;r++){
      int row = m0 + wm + i*16 + q4*4 + r;
      size_t oo = (size_t)row*N + col;
      float v = acc[i][j][r] + bv;
      if(resf) v += resf[oo];
      if(outf) outf[oo] = v;
      else     outb[oo] = f2bf(v);
    }
  }
}

// ---------- transpose V into (bh, dd, n) for PV fragment reads ----------
__global__ void k_vtrans(const u16* __restrict__ kvout, u16* __restrict__ vtg){
  int t = blockIdx.x*256 + threadIdx.x;   // 16*64*256 = 262144
  int n = t & 255, dd = (t>>8) & 63, bh = t >> 14;
  int b = bh >> 1, h = bh & 1;
  vtg[t] = kvout[((size_t)(b*256 + n))*256 + 128 + h*64 + dd];
}

// ---------- fused attention: S=QK^T*0.125+conf, softmax, O=PV ----------
__global__ __launch_bounds__(256) void k_attn(const u16* __restrict__ qb, const u16* __restrict__ kvb,
    const u16* __restrict__ vtg, const float* __restrict__ confp, u16* __restrict__ o){
  __shared__ __attribute__((aligned(16))) u16 Pl[4*16*264];
  __shared__ float cl[256];
  int bh = blockIdx.x >> 5, qblk = blockIdx.x & 31;
  int b = bh >> 1, h = bh & 1;
  int tid = threadIdx.x, lane = tid & 63, wv = tid >> 6;
  cl[tid] = confp[b*256 + tid];
  __syncthreads();
  int l16 = lane & 15, q4 = lane >> 4;
  u16* P = Pl + wv*(16*264);
  for(int it=0; it<2; it++){
    int q0 = qblk*128 + wv*32 + it*16;
    const u16* qrow = qb + ((size_t)(b*4096) + q0 + l16)*128 + h*64 + q4*8;
    bf16x8 aq0 = *(const bf16x8*)(qrow);
    bf16x8 aq1 = *(const bf16x8*)(qrow + 32);
    f32x4 sAcc[16];
    for(int nt=0; nt<16; nt++){
      const u16* krow = kvb + ((size_t)(b*256) + nt*16 + l16)*256 + h*64 + q4*8;
      bf16x8 bk0 = *(const bf16x8*)(krow);
      bf16x8 bk1 = *(const bf16x8*)(krow + 32);
      f32x4 z = (f32x4){0.f,0.f,0.f,0.f};
      z = MFMA16(aq0, bk0, z);
      z = MFMA16(aq1, bk1, z);
      sAcc[nt] = z;
    }
    float rmax[4] = {-3e38f,-3e38f,-3e38f,-3e38f};
    for(int nt=0;nt<16;nt++){
      float cb = cl[nt*16 + l16];
      for(int r=0;r<4;r++){
        float s = sAcc[nt][r]*0.125f + cb;
        sAcc[nt][r] = s;
        rmax[r] = fmaxf(rmax[r], s);
      }
    }
    for(int m=1;m<16;m<<=1)
      for(int r=0;r<4;r++) rmax[r] = fmaxf(rmax[r], __shfl_xor(rmax[r], m, 64));
    float rsum[4] = {0.f,0.f,0.f,0.f};
    for(int nt=0;nt<16;nt++)
      for(int r=0;r<4;r++){ float p = __expf(sAcc[nt][r]-rmax[r]); sAcc[nt][r]=p; rsum[r]+=p; }
    for(int m=1;m<16;m<<=1)
      for(int r=0;r<4;r++) rsum[r] += __shfl_xor(rsum[r], m, 64);
    for(int nt=0;nt<16;nt++)
      for(int r=0;r<4;r++) P[(q4*4+r)*264 + nt*16 + l16] = f2bf(sAcc[nt][r]);
    __syncthreads();
    f32x4 oAcc[4];
    for(int dt=0;dt<4;dt++) oAcc[dt] = (f32x4){0.f,0.f,0.f,0.f};
    for(int kc=0;kc<8;kc++){
      bf16x8 ap = *(const bf16x8*)(P + l16*264 + kc*32 + q4*8);
      for(int dt=0; dt<4; dt++){
        const u16* vrow = vtg + ((size_t)(bh*64) + dt*16 + l16)*256 + kc*32 + q4*8;
        bf16x8 bv = *(const bf16x8*)(vrow);
        oAcc[dt] = MFMA16(ap, bv, oAcc[dt]);
      }
    }
    float rinv[4]; for(int r=0;r<4;r++) rinv[r] = 1.f/rsum[r];
    for(int dt=0;dt<4;dt++)
      for(int r=0;r<4;r++){
        int row = q0 + q4*4 + r, col = h*64 + dt*16 + l16;
        o[((size_t)(b*4096)+row)*128 + col] = f2bf(oAcc[dt][r]*rinv[r]);
      }
    __syncthreads();
  }
}

// ---------- token2map for h (512 ch): 2 half-blocks per block, one cell each ----------
__global__ __launch_bounds__(256) void k_hmap(const u16* __restrict__ hsrc, const int* __restrict__ iagg,
    const int* __restrict__ offs_all, const int* __restrict__ list_all, u16* __restrict__ hmap){
  int gcell = blockIdx.x*2 + (threadIdx.x >> 7);
  int b = gcell >> 12, cell = gcell & 4095;
  int c0 = (threadIdx.x & 127)*4;
  int st = offs_all[b*4097+cell], en = offs_all[b*4097+cell+1];
  float a0=0.f,a1=0.f,a2=0.f,a3=0.f;
  for(int p=st;p<en;p++){
    int i = list_all[(b<<14)+p];
    int src = iagg[(b<<14)+i];
    uint2 u = *(const uint2*)(hsrc + ((size_t)(b<<12)+src)*512 + c0);
    a0 += bf2f(u.x & 0xffffu); a1 += bf2f(u.x >> 16);
    a2 += bf2f(u.y & 0xffffu); a3 += bf2f(u.y >> 16);
  }
  float inv = 1.f/fmaxf((float)(en-st), 1.f);
  uint2 o; o.x = pk2(a0*inv, a1*inv); o.y = pk2(a2*inv, a3*inv);
  *(uint2*)(hmap + ((size_t)(b<<12)+cell)*512 + c0) = o;
}

// ---------- 3x3 SAME depthwise conv + bias: 4 x-positions x 4 channels per thread ----------
__global__ __launch_bounds__(256) void k_dw(const u16* __restrict__ hmap, const float* __restrict__ dww,
    const float* __restrict__ dwb, u16* __restrict__ outm){
  int g = blockIdx.x*256 + threadIdx.x;   // 1,048,576 threads
  int cq = g & 127;
  int xg = (g>>7) & 15;
  int yy = (g>>11) & 63;
  int b  = g >> 17;
  int c0 = cq*4;
  int x0 = xg*4;
  float4 bb = *(const float4*)(dwb + c0);
  float acc[4][4];
  for(int xo=0;xo<4;xo++){ acc[xo][0]=bb.x; acc[xo][1]=bb.y; acc[xo][2]=bb.z; acc[xo][3]=bb.w; }
  for(int r=0;r<3;r++){
    int ys = yy + r - 1;
    if(ys < 0 || ys > 63) continue;            // zero padding rows
    const u16* rp = hmap + ((size_t)((b<<12) + ys*64))*512;
    float col[6][4];
    for(int cc=0;cc<6;cc++){
      int xx = x0 + cc - 1;
      uint2 u = make_uint2(0u,0u);
      if(xx >= 0 && xx <= 63) u = *(const uint2*)(rp + (size_t)xx*512 + c0);
      col[cc][0]=bf2f(u.x&0xffffu); col[cc][1]=bf2f(u.x>>16);
      col[cc][2]=bf2f(u.y&0xffffu); col[cc][3]=bf2f(u.y>>16);
    }
    for(int s=0;s<3;s++){
      float4 wv = *(const float4*)(dww + (r*3+s)*512 + c0);
      for(int xo=0;xo<4;xo++){
        acc[xo][0] += wv.x*col[xo+s][0];
        acc[xo][1] += wv.y*col[xo+s][1];
        acc[xo][2] += wv.z*col[xo+s][2];
        acc[xo][3] += wv.w*col[xo+s][3];
      }
    }
  }
  for(int xo=0;xo<4;xo++){
    int pos = (b<<12) + yy*64 + x0 + xo;
    uint2 o; o.x = pk2(acc[xo][0],acc[xo][1]); o.y = pk2(acc[xo][2],acc[xo][3]);
    *(uint2*)(outm + (size_t)pos*512 + c0) = o;
  }
}

// ---------- map2token + dwskip + GELU: 2 half-blocks per block ----------
__global__ __launch_bounds__(256) void k_m2t(const u16* __restrict__ hdw, const u16* __restrict__ hbuf,
    const float* __restrict__ aggw, const int* __restrict__ idx_hw, const int* __restrict__ offs_all,
    const int* __restrict__ list_all, const float* __restrict__ dwskip, u16* __restrict__ ht){
  int gtok = blockIdx.x*2 + (threadIdx.x >> 7);
  int b = gtok >> 12, tok = gtok & 4095;
  int c0 = (threadIdx.x & 127)*4;
  int st = offs_all[(8+b)*4097+tok], en = offs_all[(8+b)*4097+tok+1];
  float n0=0.f,n1=0.f,n2=0.f,n3=0.f,den=0.f;
  for(int p=st;p<en;p++){
    int i = list_all[((8+b)<<14)+p];
    float w = aggw[(b<<14)+i];
    int cell = idx_hw[(b<<14)+i];
    uint2 u = *(const uint2*)(hdw + ((size_t)(b<<12)+cell)*512 + c0);
    n0 += w*bf2f(u.x&0xffffu); n1 += w*bf2f(u.x>>16);
    n2 += w*bf2f(u.y&0xffffu); n3 += w*bf2f(u.y>>16);
    den += w;
  }
  float inv = 1.f/fmaxf(den, 1e-6f);
  uint2 hu = *(const uint2*)(hbuf + ((size_t)(b<<12)+tok)*512 + c0);
  float4 sk = *(const float4*)(dwskip + c0);
  float v0 = geluf(n0*inv + bf2f(hu.x&0xffffu)*sk.x);
  float v1 = geluf(n1*inv + bf2f(hu.x>>16)   *sk.y);
  float v2 = geluf(n2*inv + bf2f(hu.y&0xffffu)*sk.z);
  float v3 = geluf(n3*inv + bf2f(hu.y>>16)   *sk.w);
  uint2 o; o.x=pk2(v0,v1); o.y=pk2(v2,v3);
  *(uint2*)(ht + ((size_t)(b<<12)+tok)*512 + c0) = o;
}

extern "C" void kernel_launch(void* const* d_in, const int* in_sizes, int n_in,
                              void* d_out, int out_size, void* d_ws, size_t ws_size,
                              hipStream_t stream){
  (void)in_sizes; (void)n_in; (void)out_size; (void)ws_size;
  const float* x     = (const float*)d_in[0];
  const float* loc   = (const float*)d_in[1];
  const int*   iagg  = (const int*)d_in[2];
  const float* aggw  = (const float*)d_in[3];
  const float* xsrc  = (const float*)d_in[4];
  const int*   iaggs = (const int*)d_in[5];
  const float* confs = (const float*)d_in[6];
  const float* ln1g  = (const float*)d_in[7];
  const float* ln1b  = (const float*)d_in[8];
  const float* ln2g  = (const float*)d_in[9];
  const float* ln2b  = (const float*)d_in[10];
  const float* wq    = (const float*)d_in[11];
  const float* wkv   = (const float*)d_in[12];
  const float* wproj = (const float*)d_in[13];
  const float* bproj = (const float*)d_in[14];
  const float* srw   = (const float*)d_in[15];
  const float* srb   = (const float*)d_in[16];
  const float* srng  = (const float*)d_in[17];
  const float* srnb  = (const float*)d_in[18];
  const float* fc1w  = (const float*)d_in[19];
  const float* fc1b  = (const float*)d_in[20];
  const float* dww   = (const float*)d_in[21];
  const float* dwb   = (const float*)d_in[22];
  const float* dwskip= (const float*)d_in[23];
  const float* fc2w  = (const float*)d_in[24];
  const float* fc2b  = (const float*)d_in[25];
  float* out = (float*)d_out;

  char* ws = (char*)d_ws;
  size_t off = 0;
  auto A = [&](size_t n)->char*{ char* p = ws + off; off = (off + n + 255) & ~(size_t)255; return p; };
  // ---- zeroed block (cnt_all + conf_p contiguous; one memset) ----
  int*   cnt_all  = (int*)A(16*4096*4);
  float* conf_p   = (float*)A(8*256*4);
  // ---- small region ----
  int*   offs_all = (int*)A(16*4097*4);
  int*   cur_all  = (int*)A(16*4096*4);
  int*   list_all = (int*)A(16*16384*4);
  int*   idx_hw   = (int*)A(8*16384*4);
  u16* wqT    = (u16*)A(128*128*2);
  u16* wkvT   = (u16*)A(256*128*2);
  u16* wprojT = (u16*)A(128*128*2);
  u16* fc1T   = (u16*)A(512*128*2);
  u16* fc2T   = (u16*)A(128*512*2);
  u16* srwT   = (u16*)A(128*2048*2);
  // ---- big regions with explicit overlays (lifetimes verified disjoint) ----
  char* R0 = A(33554432);   // 32MB: xsn (dead after k_tmap) -> hbuf (fc1 out)
  char* R1 = A(33554432);   // 32MB: hmap (dead after k_dw) -> ht (m2t out)
  char* R2 = A(33554432);   // 32MB: {xn, qout, xs_part, kvout, vtg, xs} -> hdw
  char* R3 = A(8388608);    //  8MB: xs_map (dead after sr gemm) -> ybuf (ln2 out)
  char* R4 = A(16777216);   // 16MB: x1 (float, lives to end)
  u16* xsn    = (u16*)R0;  u16* hbuf = (u16*)R0;
  u16* hmap   = (u16*)R1;  u16* ht   = (u16*)R1;
  u16* xn     = (u16*)R2;
  u16* attn_o = (u16*)R2;
  u16* qout   = (u16*)(R2 + 8388608);
  float* xs_part = (float*)(R2 + 16777216);
  u16* kvout  = (u16*)(R2 + 25165824);
  u16* vtg    = (u16*)(R2 + 26214400);
  u16* xs     = (u16*)(R2 + 27262976);
  u16* hdw    = (u16*)R2;
  u16* xs_map = (u16*)R3;  u16* ybuf = (u16*)R3;
  float* x1   = (float*)R4;

  hipMemsetAsync(cnt_all, 0, 16*4096*4 + 8*256*4, stream);

  k_prep<<<dim3(2304), 256, 0, stream>>>(wq, wqT, wkv, wkvT, wproj, wprojT,
      fc1w, fc1T, fc2w, fc2T, srw, srwT, loc, iagg, idx_hw, cnt_all);

  k_ln_x2<<<dim3(2560), 256, 0, stream>>>(x, xn, xsrc, xsn, ln1g, ln1b);

  k_scan<<<dim3(16), 1024, 0, stream>>>(cnt_all, offs_all, cur_all);
  k_fill<<<dim3(512), 256, 0, stream>>>(idx_hw, iagg, cur_all, list_all);

  k_tmap<<<dim3(8192), 256, 0, stream>>>(xsn, confs, iaggs, offs_all, list_all, xs_map, conf_p);

  k_gemm_sr<<<dim3(16,4), 256, 0, stream>>>(xs_map, srwT, xs_part);
  k_ln_sr<<<dim3(32), 256, 0, stream>>>(xs_part, srb, srng, srnb, xs);

  k_gemm<<<dim3(256,1), 256, 0, stream>>>(xn, wqT, nullptr, nullptr, qout, nullptr, 32768, 128, 128);
  k_gemm<<<dim3(16,2),  256, 0, stream>>>(xs, wkvT, nullptr, nullptr, kvout, nullptr, 2048, 256, 128);
  k_vtrans<<<dim3(1024), 256, 0, stream>>>(kvout, vtg);

  k_attn<<<dim3(512), 256, 0, stream>>>(qout, kvout, vtg, conf_p, attn_o);

  k_gemm<<<dim3(256,1), 256, 0, stream>>>(attn_o, wprojT, bproj, x, nullptr, x1, 32768, 128, 128);
  k_ln_f<<<dim3(512), 256, 0, stream>>>(x1, ybuf, ln2g, ln2b, 32768);
  k_gemm<<<dim3(256,4), 256, 0, stream>>>(ybuf, fc1T, fc1b, nullptr, hbuf, nullptr, 32768, 512, 128);

  k_hmap<<<dim3(16384), 256, 0, stream>>>(hbuf, iagg, offs_all, list_all, hmap);
  k_dw<<<dim3(4096), 256, 0, stream>>>(hmap, dww, dwb, hdw);
  k_m2t<<<dim3(16384), 256, 0, stream>>>(hdw, hbuf, aggw, idx_hw, offs_all, list_all, dwskip, ht);

  k_gemm<<<dim3(256,1), 256, 0, stream>>>(ht, fc2T, fc2b, x1, nullptr, out, 32768, 128, 512);
}

// Round 6
// 483.196 us; speedup vs baseline: 1.0871x; 1.0871x over previous
//
#include <hip/hip_runtime.h>

typedef unsigned short u16;
typedef unsigned int   u32;
typedef short bf16x8 __attribute__((ext_vector_type(8)));
typedef float f32x4  __attribute__((ext_vector_type(4)));

#define MFMA16(a,b,c) __builtin_amdgcn_mfma_f32_16x16x32_bf16((a),(b),(c),0,0,0)

// ---------- bf16 helpers (storage = u16, compute = f32) ----------
__device__ __forceinline__ float bf2f(u32 u){ union{u32 i; float f;} v; v.i = u<<16; return v.f; }
__device__ __forceinline__ u16 f2bf(float f){
  union{float f; u32 i;} v; v.f=f; u32 i=v.i;
  return (u16)((i + 0x7fffu + ((i>>16)&1u)) >> 16);   // round-nearest-even
}
__device__ __forceinline__ u32 pk2(float a, float b){ return (u32)f2bf(a) | ((u32)f2bf(b)<<16); }
__device__ __forceinline__ float geluf(float x){ return 0.5f*x*(1.f + erff(x*0.7071067811865475f)); }

// ---------- fused prep: all 6 weight transposes + grid_idx/histogram ----------
__global__ void k_prep(const float* __restrict__ wq, u16* __restrict__ wqT,
                       const float* __restrict__ wkv, u16* __restrict__ wkvT,
                       const float* __restrict__ wproj, u16* __restrict__ wprojT,
                       const float* __restrict__ fc1w, u16* __restrict__ fc1T,
                       const float* __restrict__ fc2w, u16* __restrict__ fc2T,
                       const float* __restrict__ srw, u16* __restrict__ srwT,
                       const float* __restrict__ loc, const int* __restrict__ iagg,
                       int* __restrict__ idx_hw, int* __restrict__ cnt_all){
  int t = blockIdx.x*256 + threadIdx.x;
  if(t < 458752){
    const float* w; u16* wt; int li, Nsh, K;
    if(t < 16384){ w=wq; wt=wqT; li=t; Nsh=7; K=128; }
    else if(t < 49152){ w=wkv; wt=wkvT; li=t-16384; Nsh=8; K=128; }
    else if(t < 65536){ w=wproj; wt=wprojT; li=t-49152; Nsh=7; K=128; }
    else if(t < 131072){ w=fc1w; wt=fc1T; li=t-65536; Nsh=9; K=128; }
    else if(t < 196608){ w=fc2w; wt=fc2T; li=t-131072; Nsh=7; K=512; }
    else { w=srw; wt=srwT; li=t-196608; Nsh=7; K=2048; }
    int k = li >> Nsh, n = li & ((1<<Nsh)-1);
    wt[(size_t)n*K + k] = f2bf(w[li]);
  } else {
    int tid = t - 458752;          // 0..131071
    int b = tid >> 14;
    float lx = loc[(size_t)tid*2];
    float ly = loc[(size_t)tid*2+1];
    float tx = (fminf(fmaxf(lx,-1.f),1.f)+1.f)*0.5f;
    float ty = (fminf(fmaxf(ly,-1.f),1.f)+1.f)*0.5f;
    int xi = (int)rintf(tx*63.f);   // round-half-even, matches jnp.round
    int yi = (int)rintf(ty*63.f);
    int cell = yi*64 + xi;
    idx_hw[tid] = cell;
    atomicAdd(&cnt_all[b*4096 + cell], 1);
    atomicAdd(&cnt_all[(8+b)*4096 + iagg[tid]], 1);
  }
}

// ---------- LayerNorm, register-resident: 4 threads per row, 2 shuffle rounds ----------
__device__ __forceinline__ void ln_row_quarter(const float* __restrict__ in, u16* __restrict__ outp,
    const float* __restrict__ g, const float* __restrict__ bt, int part){
  const float4* src = (const float4*)(in + part*32);
  float4 v[8];
  #pragma unroll
  for(int j=0;j<8;j++) v[j] = src[j];
  float s = 0.f, ss = 0.f;
  #pragma unroll
  for(int j=0;j<8;j++){
    s  += v[j].x + v[j].y + v[j].z + v[j].w;
    ss += v[j].x*v[j].x + v[j].y*v[j].y + v[j].z*v[j].z + v[j].w*v[j].w;
  }
  s  += __shfl_xor(s,1,64);  ss += __shfl_xor(ss,1,64);
  s  += __shfl_xor(s,2,64);  ss += __shfl_xor(ss,2,64);
  float mean = s*(1.f/128.f);
  float rstd = rsqrtf(ss*(1.f/128.f) - mean*mean + 1e-5f);
  const float4* gp = (const float4*)(g + part*32);
  const float4* bp = (const float4*)(bt + part*32);
  u32 o[16];
  #pragma unroll
  for(int j=0;j<8;j++){
    float4 gg = gp[j], bb = bp[j];
    o[2*j]   = pk2((v[j].x-mean)*rstd*gg.x + bb.x, (v[j].y-mean)*rstd*gg.y + bb.y);
    o[2*j+1] = pk2((v[j].z-mean)*rstd*gg.z + bb.z, (v[j].w-mean)*rstd*gg.w + bb.w);
  }
  int4* dst = (int4*)(outp + part*32);
  #pragma unroll
  for(int j=0;j<4;j++) dst[j] = ((const int4*)o)[j];
}

__global__ __launch_bounds__(256) void k_ln_x2(const float* __restrict__ in0, u16* __restrict__ out0,
    const float* __restrict__ in1, u16* __restrict__ out1,
    const float* __restrict__ g, const float* __restrict__ bt){
  int t = blockIdx.x*256 + threadIdx.x;
  int row = t >> 2, part = t & 3;
  const float* in; u16* outp;
  if(row < 32768){ in = in0 + (size_t)row*128; outp = out0 + (size_t)row*128; }
  else { int r2 = row - 32768; in = in1 + (size_t)r2*128; outp = out1 + (size_t)r2*128; }
  ln_row_quarter(in, outp, g, bt, part);
}

__global__ __launch_bounds__(256) void k_ln_f(const float* __restrict__ in, u16* __restrict__ outp,
    const float* __restrict__ g, const float* __restrict__ bt, int rows){
  int t = blockIdx.x*256 + threadIdx.x;
  int row = t >> 2, part = t & 3;
  if(row >= rows) return;
  ln_row_quarter(in + (size_t)row*128, outp + (size_t)row*128, g, bt, part);
}

// ---------- LN over sum of 4 split-K partials + conv bias (register-resident) ----------
__global__ __launch_bounds__(256) void k_ln_sr(const float* __restrict__ part, const float* __restrict__ srb,
    const float* __restrict__ g, const float* __restrict__ bt, u16* __restrict__ outp){
  int t = blockIdx.x*256 + threadIdx.x;     // 2048 rows * 4 = 8192 threads
  int row = t >> 2, pq = t & 3;
  const float4* p0 = (const float4*)(part +            (size_t)row*128 + pq*32);
  const float4* p1 = (const float4*)(part + 262144  +  (size_t)row*128 + pq*32);
  const float4* p2 = (const float4*)(part + 524288  +  (size_t)row*128 + pq*32);
  const float4* p3 = (const float4*)(part + 786432  +  (size_t)row*128 + pq*32);
  const float4* sb = (const float4*)(srb + pq*32);
  float4 v[8];
  float s = 0.f, ss = 0.f;
  #pragma unroll
  for(int j=0;j<8;j++){
    float4 a = p0[j], b2 = p1[j], c = p2[j], d = p3[j], e = sb[j];
    v[j].x = a.x+b2.x+c.x+d.x+e.x;
    v[j].y = a.y+b2.y+c.y+d.y+e.y;
    v[j].z = a.z+b2.z+c.z+d.z+e.z;
    v[j].w = a.w+b2.w+c.w+d.w+e.w;
    s  += v[j].x + v[j].y + v[j].z + v[j].w;
    ss += v[j].x*v[j].x + v[j].y*v[j].y + v[j].z*v[j].z + v[j].w*v[j].w;
  }
  s  += __shfl_xor(s,1,64);  ss += __shfl_xor(ss,1,64);
  s  += __shfl_xor(s,2,64);  ss += __shfl_xor(ss,2,64);
  float mean = s*(1.f/128.f);
  float rstd = rsqrtf(ss*(1.f/128.f) - mean*mean + 1e-5f);
  const float4* gp = (const float4*)(g + pq*32);
  const float4* bp = (const float4*)(bt + pq*32);
  u32 o[16];
  #pragma unroll
  for(int j=0;j<8;j++){
    float4 gg = gp[j], bb = bp[j];
    o[2*j]   = pk2((v[j].x-mean)*rstd*gg.x + bb.x, (v[j].y-mean)*rstd*gg.y + bb.y);
    o[2*j+1] = pk2((v[j].z-mean)*rstd*gg.z + bb.z, (v[j].w-mean)*rstd*gg.w + bb.w);
  }
  int4* dst = (int4*)(outp + (size_t)row*128 + pq*32);
  #pragma unroll
  for(int j=0;j<4;j++) dst[j] = ((const int4*)o)[j];
}

// ---------- exclusive scan of 4096 counts per (b,grouping); 16 blocks ----------
__global__ __launch_bounds__(1024) void k_scan(const int* __restrict__ cnt_all,
    int* __restrict__ offs_all, int* __restrict__ cur_all){
  int g = blockIdx.x;
  const int* src = cnt_all + g*4096;
  int* offs = offs_all + g*4097;
  int* cur  = cur_all  + g*4096;
  __shared__ int part[1024];
  int t = threadIdx.x;
  int v0=src[4*t], v1=src[4*t+1], v2=src[4*t+2], v3=src[4*t+3];
  int s = v0+v1+v2+v3;
  part[t] = s; __syncthreads();
  for(int off=1; off<1024; off<<=1){
    int x = (t>=off) ? part[t-off] : 0;
    __syncthreads();
    part[t] += x;
    __syncthreads();
  }
  int base = part[t] - s;
  offs[4*t]   = base;          cur[4*t]   = base;
  offs[4*t+1] = base+v0;       cur[4*t+1] = base+v0;
  offs[4*t+2] = base+v0+v1;    cur[4*t+2] = base+v0+v1;
  offs[4*t+3] = base+v0+v1+v2; cur[4*t+3] = base+v0+v1+v2;
  if(t==1023) offs[4096] = base+s;
}

// ---------- fill sorted point lists ----------
__global__ void k_fill(const int* __restrict__ idx_hw, const int* __restrict__ iagg,
                       int* __restrict__ cur_all, int* __restrict__ list_all){
  int tid = blockIdx.x*256 + threadIdx.x;
  int b = tid >> 14, i = tid & 16383;
  int cell = idx_hw[tid];
  int p = atomicAdd(&cur_all[b*4096 + cell], 1);
  list_all[(b<<14) + p] = i;
  int tok = iagg[tid];
  p = atomicAdd(&cur_all[(8+b)*4096 + tok], 1);
  list_all[((8+b)<<14) + p] = i;
}

// ---------- token2map for [xsn | conf]: one cell per 64-thr block, 4-point pipelined ----------
__global__ __launch_bounds__(64) void k_tmap(const u16* __restrict__ xsn, const float* __restrict__ confs,
    const int* __restrict__ iaggs, const int* __restrict__ offs_all, const int* __restrict__ list_all,
    u16* __restrict__ xs_map, float* __restrict__ conf_p){
  int b = blockIdx.x >> 12, cell = blockIdx.x & 4095;
  int lane = threadIdx.x;
  int st = offs_all[b*4097 + cell], en = offs_all[b*4097 + cell + 1];
  float a0=0.f, a1=0.f, cf=0.f;
  for(int p=st;p<en;p+=4){
    int idx[4]; float vm[4];
    #pragma unroll
    for(int j=0;j<4;j++){
      int pj = (p+j < en) ? p+j : en-1;
      vm[j] = (p+j < en) ? 1.f : 0.f;
      idx[j] = list_all[(b<<14)+pj];
    }
    int src[4];
    #pragma unroll
    for(int j=0;j<4;j++) src[j] = iaggs[(b<<14)+idx[j]];
    u32 u[4]; float cfv[4];
    #pragma unroll
    for(int j=0;j<4;j++){
      u[j]   = ((const u32*)(xsn + ((size_t)(b<<14)+src[j])*128))[lane];
      cfv[j] = confs[(b<<14)+src[j]];
    }
    #pragma unroll
    for(int j=0;j<4;j++){
      a0 += vm[j]*bf2f(u[j] & 0xffffu);
      a1 += vm[j]*bf2f(u[j] >> 16);
      cf += vm[j]*cfv[j];
    }
  }
  float inv = 1.f/fmaxf((float)(en-st), 1.f);
  ((u32*)(xs_map + ((size_t)(b<<12)+cell)*128))[lane] = pk2(a0*inv, a1*inv);
  if(lane==0){
    int ci = ((cell>>8)<<4) + ((cell&63)>>2);   // (yi/4)*16 + (xi/4)
    atomicAdd(&conf_p[b*256 + ci], cf*inv*(1.f/16.f));
  }
}

// ---------- sr-conv GEMM, split-K=4, im2col fused into A staging ----------
__global__ __launch_bounds__(256) void k_gemm_sr(const u16* __restrict__ xs_map, const u16* __restrict__ Wt,
    float* __restrict__ part){
  __shared__ __attribute__((aligned(16))) u16 lA[128*80];
  __shared__ __attribute__((aligned(16))) u16 lB[128*80];
  int m0 = blockIdx.x*128;
  int kbase = blockIdx.y*512;
  int tid = threadIdx.x, lane = tid & 63, wv = tid >> 6;
  int wm = (wv>>1)*64, wn = (wv&1)*64;
  int l16 = lane & 15, q4 = lane >> 4;
  f32x4 acc[4][4];
  for(int i=0;i<4;i++) for(int j=0;j<4;j++) acc[i][j] = (f32x4){0.f,0.f,0.f,0.f};
  for(int k0=kbase; k0<kbase+512; k0+=64){
    __syncthreads();
    for(int s=0;s<4;s++){
      int c = tid + s*256;
      int row = c >> 3, ko = (c & 7)*8;
      int m = m0 + row, k = k0 + ko;
      int b = m >> 8, oc = m & 255;
      int oy = oc >> 4, ox = oc & 15;
      int pos = k >> 7, ch = k & 127;
      int r = pos >> 2, ssp = pos & 3;
      int gy = oy*4 + r, gx = ox*4 + ssp;
      *(int4*)(lA + row*80 + ko) =
          *(const int4*)(xs_map + ((size_t)(b*4096) + gy*64 + gx)*128 + ch);
      *(int4*)(lB + row*80 + ko) = *(const int4*)(Wt + (size_t)row*2048 + k);
    }
    __syncthreads();
    for(int kk=0;kk<64;kk+=32){
      bf16x8 af[4], bfr[4];
      for(int i=0;i<4;i++) af[i]  = *(const bf16x8*)(lA + (wm + i*16 + l16)*80 + kk + q4*8);
      for(int j=0;j<4;j++) bfr[j] = *(const bf16x8*)(lB + (wn + j*16 + l16)*80 + kk + q4*8);
      for(int i=0;i<4;i++)
        for(int j=0;j<4;j++)
          acc[i][j] = MFMA16(af[i], bfr[j], acc[i][j]);
    }
  }
  float* outp = part + (size_t)blockIdx.y*262144;
  for(int i=0;i<4;i++) for(int j=0;j<4;j++){
    int col = wn + j*16 + l16;
    for(int r=0;r<4;r++){
      int row = m0 + wm + i*16 + q4*4 + r;
      outp[(size_t)row*128 + col] = acc[i][j][r];
    }
  }
}

// ---------- bf16 MFMA GEMM: out[M,N] = A[M,K] @ Wt[N,K]^T (+f32 bias)(+f32 res) ----------
__global__ __launch_bounds__(256) void k_gemm(const u16* __restrict__ Ag, const u16* __restrict__ Wt,
    const float* __restrict__ bias, const float* __restrict__ resf,
    u16* __restrict__ outb, float* __restrict__ outf, int M, int N, int K){
  __shared__ __attribute__((aligned(16))) u16 lA[128*80];
  __shared__ __attribute__((aligned(16))) u16 lB[128*80];
  int m0 = blockIdx.x*128, n0 = blockIdx.y*128;
  int tid = threadIdx.x, lane = tid & 63, wv = tid >> 6;
  int wm = (wv>>1)*64, wn = (wv&1)*64;
  int l16 = lane & 15, q4 = lane >> 4;
  f32x4 acc[4][4];
  for(int i=0;i<4;i++) for(int j=0;j<4;j++) acc[i][j] = (f32x4){0.f,0.f,0.f,0.f};
  for(int k0=0;k0<K;k0+=64){
    __syncthreads();
    for(int s=0;s<4;s++){
      int c = tid + s*256;
      int row = c >> 3, ko = (c & 7)*8;
      *(int4*)(lA + row*80 + ko) = *(const int4*)(Ag + (size_t)(m0+row)*K + k0 + ko);
      *(int4*)(lB + row*80 + ko) = *(const int4*)(Wt + (size_t)(n0+row)*K + k0 + ko);
    }
    __syncthreads();
    for(int kk=0;kk<64;kk+=32){
      bf16x8 af[4], bfr[4];
      for(int i=0;i<4;i++) af[i]  = *(const bf16x8*)(lA + (wm + i*16 + l16)*80 + kk + q4*8);
      for(int j=0;j<4;j++) bfr[j] = *(const bf16x8*)(lB + (wn + j*16 + l16)*80 + kk + q4*8);
      for(int i=0;i<4;i++)
        for(int j=0;j<4;j++)
          acc[i][j] = MFMA16(af[i], bfr[j], acc[i][j]);
    }
  }
  for(int i=0;i<4;i++) for(int j=0;j<4;j++){
    int col = n0 + wn + j*16 + l16;
    float bv = bias ? bias[col] : 0.f;
    for(int r=0;r<4;r++){
      int row = m0 + wm + i*16 + q4*4 + r;
      size_t oo = (size_t)row*N + col;
      float v = acc[i][j][r] + bv;
      if(resf) v += resf[oo];
      if(outf) outf[oo] = v;
      else     outb[oo] = f2bf(v);
    }
  }
}

// ---------- transpose V into (bh, dd, n) for PV fragment reads ----------
__global__ void k_vtrans(const u16* __restrict__ kvout, u16* __restrict__ vtg){
  int t = blockIdx.x*256 + threadIdx.x;   // 16*64*256 = 262144
  int n = t & 255, dd = (t>>8) & 63, bh = t >> 14;
  int b = bh >> 1, h = bh & 1;
  vtg[t] = kvout[((size_t)(b*256 + n))*256 + 128 + h*64 + dd];
}

// ---------- fused attention: S=QK^T*0.125+conf, softmax, O=PV ----------
__global__ __launch_bounds__(256) void k_attn(const u16* __restrict__ qb, const u16* __restrict__ kvb,
    const u16* __restrict__ vtg, const float* __restrict__ confp, u16* __restrict__ o){
  __shared__ __attribute__((aligned(16))) u16 Pl[4*16*264];
  __shared__ float cl[256];
  int bh = blockIdx.x >> 5, qblk = blockIdx.x & 31;
  int b = bh >> 1, h = bh & 1;
  int tid = threadIdx.x, lane = tid & 63, wv = tid >> 6;
  cl[tid] = confp[b*256 + tid];
  __syncthreads();
  int l16 = lane & 15, q4 = lane >> 4;
  u16* P = Pl + wv*(16*264);
  for(int it=0; it<2; it++){
    int q0 = qblk*128 + wv*32 + it*16;
    const u16* qrow = qb + ((size_t)(b*4096) + q0 + l16)*128 + h*64 + q4*8;
    bf16x8 aq0 = *(const bf16x8*)(qrow);
    bf16x8 aq1 = *(const bf16x8*)(qrow + 32);
    f32x4 sAcc[16];
    for(int nt=0; nt<16; nt++){
      const u16* krow = kvb + ((size_t)(b*256) + nt*16 + l16)*256 + h*64 + q4*8;
      bf16x8 bk0 = *(const bf16x8*)(krow);
      bf16x8 bk1 = *(const bf16x8*)(krow + 32);
      f32x4 z = (f32x4){0.f,0.f,0.f,0.f};
      z = MFMA16(aq0, bk0, z);
      z = MFMA16(aq1, bk1, z);
      sAcc[nt] = z;
    }
    float rmax[4] = {-3e38f,-3e38f,-3e38f,-3e38f};
    for(int nt=0;nt<16;nt++){
      float cb = cl[nt*16 + l16];
      for(int r=0;r<4;r++){
        float s = sAcc[nt][r]*0.125f + cb;
        sAcc[nt][r] = s;
        rmax[r] = fmaxf(rmax[r], s);
      }
    }
    for(int m=1;m<16;m<<=1)
      for(int r=0;r<4;r++) rmax[r] = fmaxf(rmax[r], __shfl_xor(rmax[r], m, 64));
    float rsum[4] = {0.f,0.f,0.f,0.f};
    for(int nt=0;nt<16;nt++)
      for(int r=0;r<4;r++){ float p = __expf(sAcc[nt][r]-rmax[r]); sAcc[nt][r]=p; rsum[r]+=p; }
    for(int m=1;m<16;m<<=1)
      for(int r=0;r<4;r++) rsum[r] += __shfl_xor(rsum[r], m, 64);
    for(int nt=0;nt<16;nt++)
      for(int r=0;r<4;r++) P[(q4*4+r)*264 + nt*16 + l16] = f2bf(sAcc[nt][r]);
    __syncthreads();
    f32x4 oAcc[4];
    for(int dt=0;dt<4;dt++) oAcc[dt] = (f32x4){0.f,0.f,0.f,0.f};
    for(int kc=0;kc<8;kc++){
      bf16x8 ap = *(const bf16x8*)(P + l16*264 + kc*32 + q4*8);
      for(int dt=0; dt<4; dt++){
        const u16* vrow = vtg + ((size_t)(bh*64) + dt*16 + l16)*256 + kc*32 + q4*8;
        bf16x8 bv = *(const bf16x8*)(vrow);
        oAcc[dt] = MFMA16(ap, bv, oAcc[dt]);
      }
    }
    float rinv[4]; for(int r=0;r<4;r++) rinv[r] = 1.f/rsum[r];
    for(int dt=0;dt<4;dt++)
      for(int r=0;r<4;r++){
        int row = q0 + q4*4 + r, col = h*64 + dt*16 + l16;
        o[((size_t)(b*4096)+row)*128 + col] = f2bf(oAcc[dt][r]*rinv[r]);
      }
    __syncthreads();
  }
}

// ---------- token2map for h (512 ch): one cell per 128-thr block, 4-point pipelined ----------
__global__ __launch_bounds__(128) void k_hmap(const u16* __restrict__ hsrc, const int* __restrict__ iagg,
    const int* __restrict__ offs_all, const int* __restrict__ list_all, u16* __restrict__ hmap){
  int b = blockIdx.x >> 12, cell = blockIdx.x & 4095;
  int c0 = threadIdx.x*4;
  int st = offs_all[b*4097+cell], en = offs_all[b*4097+cell+1];
  float a0=0.f,a1=0.f,a2=0.f,a3=0.f;
  for(int p=st;p<en;p+=4){
    int idx[4]; float vm[4];
    #pragma unroll
    for(int j=0;j<4;j++){
      int pj = (p+j < en) ? p+j : en-1;
      vm[j] = (p+j < en) ? 1.f : 0.f;
      idx[j] = list_all[(b<<14)+pj];
    }
    int src[4];
    #pragma unroll
    for(int j=0;j<4;j++) src[j] = iagg[(b<<14)+idx[j]];
    uint2 u[4];
    #pragma unroll
    for(int j=0;j<4;j++) u[j] = *(const uint2*)(hsrc + ((size_t)(b<<12)+src[j])*512 + c0);
    #pragma unroll
    for(int j=0;j<4;j++){
      a0 += vm[j]*bf2f(u[j].x & 0xffffu); a1 += vm[j]*bf2f(u[j].x >> 16);
      a2 += vm[j]*bf2f(u[j].y & 0xffffu); a3 += vm[j]*bf2f(u[j].y >> 16);
    }
  }
  float inv = 1.f/fmaxf((float)(en-st), 1.f);
  uint2 o; o.x = pk2(a0*inv, a1*inv); o.y = pk2(a2*inv, a3*inv);
  *(uint2*)(hmap + ((size_t)(b<<12)+cell)*512 + c0) = o;
}

// ---------- 3x3 SAME depthwise conv + bias: 4 x-positions x 4 channels per thread ----------
__global__ __launch_bounds__(256) void k_dw(const u16* __restrict__ hmap, const float* __restrict__ dww,
    const float* __restrict__ dwb, u16* __restrict__ outm){
  int g = blockIdx.x*256 + threadIdx.x;   // 1,048,576 threads
  int cq = g & 127;
  int xg = (g>>7) & 15;
  int yy = (g>>11) & 63;
  int b  = g >> 17;
  int c0 = cq*4;
  int x0 = xg*4;
  float4 bb = *(const float4*)(dwb + c0);
  float acc[4][4];
  for(int xo=0;xo<4;xo++){ acc[xo][0]=bb.x; acc[xo][1]=bb.y; acc[xo][2]=bb.z; acc[xo][3]=bb.w; }
  for(int r=0;r<3;r++){
    int ys = yy + r - 1;
    if(ys < 0 || ys > 63) continue;            // zero padding rows
    const u16* rp = hmap + ((size_t)((b<<12) + ys*64))*512;
    float col[6][4];
    for(int cc=0;cc<6;cc++){
      int xx = x0 + cc - 1;
      uint2 u = make_uint2(0u,0u);
      if(xx >= 0 && xx <= 63) u = *(const uint2*)(rp + (size_t)xx*512 + c0);
      col[cc][0]=bf2f(u.x&0xffffu); col[cc][1]=bf2f(u.x>>16);
      col[cc][2]=bf2f(u.y&0xffffu); col[cc][3]=bf2f(u.y>>16);
    }
    for(int s=0;s<3;s++){
      float4 wv = *(const float4*)(dww + (r*3+s)*512 + c0);
      for(int xo=0;xo<4;xo++){
        acc[xo][0] += wv.x*col[xo+s][0];
        acc[xo][1] += wv.y*col[xo+s][1];
        acc[xo][2] += wv.z*col[xo+s][2];
        acc[xo][3] += wv.w*col[xo+s][3];
      }
    }
  }
  for(int xo=0;xo<4;xo++){
    int pos = (b<<12) + yy*64 + x0 + xo;
    uint2 o; o.x = pk2(acc[xo][0],acc[xo][1]); o.y = pk2(acc[xo][2],acc[xo][3]);
    *(uint2*)(outm + (size_t)pos*512 + c0) = o;
  }
}

// ---------- map2token + dwskip + GELU: one token per 128-thr block, 4-point pipelined ----------
__global__ __launch_bounds__(128) void k_m2t(const u16* __restrict__ hdw, const u16* __restrict__ hbuf,
    const float* __restrict__ aggw, const int* __restrict__ idx_hw, const int* __restrict__ offs_all,
    const int* __restrict__ list_all, const float* __restrict__ dwskip, u16* __restrict__ ht){
  int b = blockIdx.x >> 12, tok = blockIdx.x & 4095;
  int c0 = threadIdx.x*4;
  int st = offs_all[(8+b)*4097+tok], en = offs_all[(8+b)*4097+tok+1];
  float n0=0.f,n1=0.f,n2=0.f,n3=0.f,den=0.f;
  for(int p=st;p<en;p+=4){
    int idx[4]; float vm[4];
    #pragma unroll
    for(int j=0;j<4;j++){
      int pj = (p+j < en) ? p+j : en-1;
      vm[j] = (p+j < en) ? 1.f : 0.f;
      idx[j] = list_all[((8+b)<<14)+pj];
    }
    float w[4]; int cell[4];
    #pragma unroll
    for(int j=0;j<4;j++){
      w[j] = vm[j]*aggw[(b<<14)+idx[j]];
      cell[j] = idx_hw[(b<<14)+idx[j]];
    }
    uint2 u[4];
    #pragma unroll
    for(int j=0;j<4;j++) u[j] = *(const uint2*)(hdw + ((size_t)(b<<12)+cell[j])*512 + c0);
    #pragma unroll
    for(int j=0;j<4;j++){
      n0 += w[j]*bf2f(u[j].x & 0xffffu); n1 += w[j]*bf2f(u[j].x >> 16);
      n2 += w[j]*bf2f(u[j].y & 0xffffu); n3 += w[j]*bf2f(u[j].y >> 16);
      den += w[j];
    }
  }
  float inv = 1.f/fmaxf(den, 1e-6f);
  uint2 hu = *(const uint2*)(hbuf + ((size_t)(b<<12)+tok)*512 + c0);
  float4 sk = *(const float4*)(dwskip + c0);
  float v0 = geluf(n0*inv + bf2f(hu.x&0xffffu)*sk.x);
  float v1 = geluf(n1*inv + bf2f(hu.x>>16)   *sk.y);
  float v2 = geluf(n2*inv + bf2f(hu.y&0xffffu)*sk.z);
  float v3 = geluf(n3*inv + bf2f(hu.y>>16)   *sk.w);
  uint2 o; o.x=pk2(v0,v1); o.y=pk2(v2,v3);
  *(uint2*)(ht + ((size_t)(b<<12)+tok)*512 + c0) = o;
}

extern "C" void kernel_launch(void* const* d_in, const int* in_sizes, int n_in,
                              void* d_out, int out_size, void* d_ws, size_t ws_size,
                              hipStream_t stream){
  (void)in_sizes; (void)n_in; (void)out_size; (void)ws_size;
  const float* x     = (const float*)d_in[0];
  const float* loc   = (const float*)d_in[1];
  const int*   iagg  = (const int*)d_in[2];
  const float* aggw  = (const float*)d_in[3];
  const float* xsrc  = (const float*)d_in[4];
  const int*   iaggs = (const int*)d_in[5];
  const float* confs = (const float*)d_in[6];
  const float* ln1g  = (const float*)d_in[7];
  const float* ln1b  = (const float*)d_in[8];
  const float* ln2g  = (const float*)d_in[9];
  const float* ln2b  = (const float*)d_in[10];
  const float* wq    = (const float*)d_in[11];
  const float* wkv   = (const float*)d_in[12];
  const float* wproj = (const float*)d_in[13];
  const float* bproj = (const float*)d_in[14];
  const float* srw   = (const float*)d_in[15];
  const float* srb   = (const float*)d_in[16];
  const float* srng  = (const float*)d_in[17];
  const float* srnb  = (const float*)d_in[18];
  const float* fc1w  = (const float*)d_in[19];
  const float* fc1b  = (const float*)d_in[20];
  const float* dww   = (const float*)d_in[21];
  const float* dwb   = (const float*)d_in[22];
  const float* dwskip= (const float*)d_in[23];
  const float* fc2w  = (const float*)d_in[24];
  const float* fc2b  = (const float*)d_in[25];
  float* out = (float*)d_out;

  char* ws = (char*)d_ws;
  size_t off = 0;
  auto A = [&](size_t n)->char*{ char* p = ws + off; off = (off + n + 255) & ~(size_t)255; return p; };
  // ---- zeroed block (cnt_all + conf_p contiguous; one memset) ----
  int*   cnt_all  = (int*)A(16*4096*4);
  float* conf_p   = (float*)A(8*256*4);
  // ---- small region ----
  int*   offs_all = (int*)A(16*4097*4);
  int*   cur_all  = (int*)A(16*4096*4);
  int*   list_all = (int*)A(16*16384*4);
  int*   idx_hw   = (int*)A(8*16384*4);
  u16* wqT    = (u16*)A(128*128*2);
  u16* wkvT   = (u16*)A(256*128*2);
  u16* wprojT = (u16*)A(128*128*2);
  u16* fc1T   = (u16*)A(512*128*2);
  u16* fc2T   = (u16*)A(128*512*2);
  u16* srwT   = (u16*)A(128*2048*2);
  // ---- big regions with explicit overlays (lifetimes verified disjoint) ----
  char* R0 = A(33554432);   // 32MB: xsn (dead after k_tmap) -> hbuf (fc1 out)
  char* R1 = A(33554432);   // 32MB: hmap (dead after k_dw) -> ht (m2t out)
  char* R2 = A(33554432);   // 32MB: {xn, qout, xs_part, kvout, vtg, xs} -> hdw
  char* R3 = A(8388608);    //  8MB: xs_map (dead after sr gemm) -> ybuf (ln2 out)
  char* R4 = A(16777216);   // 16MB: x1 (float, lives to end)
  u16* xsn    = (u16*)R0;  u16* hbuf = (u16*)R0;
  u16* hmap   = (u16*)R1;  u16* ht   = (u16*)R1;
  u16* xn     = (u16*)R2;
  u16* attn_o = (u16*)R2;
  u16* qout   = (u16*)(R2 + 8388608);
  float* xs_part = (float*)(R2 + 16777216);
  u16* kvout  = (u16*)(R2 + 25165824);
  u16* vtg    = (u16*)(R2 + 26214400);
  u16* xs     = (u16*)(R2 + 27262976);
  u16* hdw    = (u16*)R2;
  u16* xs_map = (u16*)R3;  u16* ybuf = (u16*)R3;
  float* x1   = (float*)R4;

  hipMemsetAsync(cnt_all, 0, 16*4096*4 + 8*256*4, stream);

  k_prep<<<dim3(2304), 256, 0, stream>>>(wq, wqT, wkv, wkvT, wproj, wprojT,
      fc1w, fc1T, fc2w, fc2T, srw, srwT, loc, iagg, idx_hw, cnt_all);

  k_ln_x2<<<dim3(2560), 256, 0, stream>>>(x, xn, xsrc, xsn, ln1g, ln1b);

  k_scan<<<dim3(16), 1024, 0, stream>>>(cnt_all, offs_all, cur_all);
  k_fill<<<dim3(512), 256, 0, stream>>>(idx_hw, iagg, cur_all, list_all);

  k_tmap<<<dim3(32768), 64, 0, stream>>>(xsn, confs, iaggs, offs_all, list_all, xs_map, conf_p);

  k_gemm_sr<<<dim3(16,4), 256, 0, stream>>>(xs_map, srwT, xs_part);
  k_ln_sr<<<dim3(32), 256, 0, stream>>>(xs_part, srb, srng, srnb, xs);

  k_gemm<<<dim3(256,1), 256, 0, stream>>>(xn, wqT, nullptr, nullptr, qout, nullptr, 32768, 128, 128);
  k_gemm<<<dim3(16,2),  256, 0, stream>>>(xs, wkvT, nullptr, nullptr, kvout, nullptr, 2048, 256, 128);
  k_vtrans<<<dim3(1024), 256, 0, stream>>>(kvout, vtg);

  k_attn<<<dim3(512), 256, 0, stream>>>(qout, kvout, vtg, conf_p, attn_o);

  k_gemm<<<dim3(256,1), 256, 0, stream>>>(attn_o, wprojT, bproj, x, nullptr, x1, 32768, 128, 128);
  k_ln_f<<<dim3(512), 256, 0, stream>>>(x1, ybuf, ln2g, ln2b, 32768);
  k_gemm<<<dim3(256,4), 256, 0, stream>>>(ybuf, fc1T, fc1b, nullptr, hbuf, nullptr, 32768, 512, 128);

  k_hmap<<<dim3(32768), 128, 0, stream>>>(hbuf, iagg, offs_all, list_all, hmap);
  k_dw<<<dim3(4096), 256, 0, stream>>>(hmap, dww, dwb, hdw);
  k_m2t<<<dim3(32768), 128, 0, stream>>>(hdw, hbuf, aggw, idx_hw, offs_all, list_all, dwskip, ht);

  k_gemm<<<dim3(256,1), 256, 0, stream>>>(ht, fc2T, fc2b, x1, nullptr, out, 32768, 128, 512);
}

// Round 7
// 443.174 us; speedup vs baseline: 1.1853x; 1.0903x over previous
//
#include <hip/hip_runtime.h>

typedef unsigned short u16;
typedef unsigned int   u32;
typedef short bf16x8 __attribute__((ext_vector_type(8)));
typedef float f32x4  __attribute__((ext_vector_type(4)));

#define MFMA16(a,b,c) __builtin_amdgcn_mfma_f32_16x16x32_bf16((a),(b),(c),0,0,0)

// ---------- bf16 helpers (storage = u16, compute = f32) ----------
__device__ __forceinline__ float bf2f(u32 u){ union{u32 i; float f;} v; v.i = u<<16; return v.f; }
__device__ __forceinline__ u16 f2bf(float f){
  union{float f; u32 i;} v; v.f=f; u32 i=v.i;
  return (u16)((i + 0x7fffu + ((i>>16)&1u)) >> 16);   // round-nearest-even
}
__device__ __forceinline__ u32 pk2(float a, float b){ return (u32)f2bf(a) | ((u32)f2bf(b)<<16); }
__device__ __forceinline__ float geluf(float x){ return 0.5f*x*(1.f + erff(x*0.7071067811865475f)); }

// ---------- fused prep: all 6 weight transposes + grid_idx/histogram ----------
__global__ void k_prep(const float* __restrict__ wq, u16* __restrict__ wqT,
                       const float* __restrict__ wkv, u16* __restrict__ wkvT,
                       const float* __restrict__ wproj, u16* __restrict__ wprojT,
                       const float* __restrict__ fc1w, u16* __restrict__ fc1T,
                       const float* __restrict__ fc2w, u16* __restrict__ fc2T,
                       const float* __restrict__ srw, u16* __restrict__ srwT,
                       const float* __restrict__ loc, const int* __restrict__ iagg,
                       int* __restrict__ idx_hw, int* __restrict__ cnt_all){
  int t = blockIdx.x*256 + threadIdx.x;
  if(t < 458752){
    const float* w; u16* wt; int li, Nsh, K;
    if(t < 16384){ w=wq; wt=wqT; li=t; Nsh=7; K=128; }
    else if(t < 49152){ w=wkv; wt=wkvT; li=t-16384; Nsh=8; K=128; }
    else if(t < 65536){ w=wproj; wt=wprojT; li=t-49152; Nsh=7; K=128; }
    else if(t < 131072){ w=fc1w; wt=fc1T; li=t-65536; Nsh=9; K=128; }
    else if(t < 196608){ w=fc2w; wt=fc2T; li=t-131072; Nsh=7; K=512; }
    else { w=srw; wt=srwT; li=t-196608; Nsh=7; K=2048; }
    int k = li >> Nsh, n = li & ((1<<Nsh)-1);
    wt[(size_t)n*K + k] = f2bf(w[li]);
  } else {
    int tid = t - 458752;          // 0..131071
    int b = tid >> 14;
    float lx = loc[(size_t)tid*2];
    float ly = loc[(size_t)tid*2+1];
    float tx = (fminf(fmaxf(lx,-1.f),1.f)+1.f)*0.5f;
    float ty = (fminf(fmaxf(ly,-1.f),1.f)+1.f)*0.5f;
    int xi = (int)rintf(tx*63.f);   // round-half-even, matches jnp.round
    int yi = (int)rintf(ty*63.f);
    int cell = yi*64 + xi;
    idx_hw[tid] = cell;
    atomicAdd(&cnt_all[b*4096 + cell], 1);
    atomicAdd(&cnt_all[(8+b)*4096 + iagg[tid]], 1);
  }
}

// ---------- LayerNorm, half-wave per row: lane c loads float4 at row*512+c*16 ----------
// fully coalesced 1KB/instruction; 5 shuffle rounds within 32 lanes; 8B/lane store.
__global__ __launch_bounds__(256) void k_ln1(const float* __restrict__ in, u16* __restrict__ outp,
    const float* __restrict__ g, const float* __restrict__ bt){
  int t = blockIdx.x*256 + threadIdx.x;
  int row = t >> 5, c = t & 31;
  float4 v = ((const float4*)(in + (size_t)row*128))[c];
  float s  = v.x + v.y + v.z + v.w;
  float ss = v.x*v.x + v.y*v.y + v.z*v.z + v.w*v.w;
  #pragma unroll
  for(int m=1;m<32;m<<=1){ s += __shfl_xor(s,m,64); ss += __shfl_xor(ss,m,64); }
  float mean = s*(1.f/128.f);
  float rstd = rsqrtf(ss*(1.f/128.f) - mean*mean + 1e-5f);
  float4 gg = ((const float4*)g)[c];
  float4 bb = ((const float4*)bt)[c];
  uint2 o;
  o.x = pk2((v.x-mean)*rstd*gg.x + bb.x, (v.y-mean)*rstd*gg.y + bb.y);
  o.y = pk2((v.z-mean)*rstd*gg.z + bb.z, (v.w-mean)*rstd*gg.w + bb.w);
  ((uint2*)(outp + (size_t)row*128))[c] = o;
}

// ---------- LN over sum of 4 split-K partials + conv bias ----------
__global__ __launch_bounds__(256) void k_ln_sr(const float* __restrict__ part, const float* __restrict__ srb,
    const float* __restrict__ g, const float* __restrict__ bt, u16* __restrict__ outp){
  int t = blockIdx.x*256 + threadIdx.x;     // 2048 rows * 32 = 65536 threads
  int row = t >> 5, c = t & 31;
  const float4* p0 = (const float4*)(part +           (size_t)row*128);
  const float4* p1 = (const float4*)(part + 262144 +  (size_t)row*128);
  const float4* p2 = (const float4*)(part + 524288 +  (size_t)row*128);
  const float4* p3 = (const float4*)(part + 786432 +  (size_t)row*128);
  float4 a = p0[c], b2 = p1[c], cc = p2[c], d = p3[c];
  float4 e = ((const float4*)srb)[c];
  float4 v;
  v.x = a.x+b2.x+cc.x+d.x+e.x;
  v.y = a.y+b2.y+cc.y+d.y+e.y;
  v.z = a.z+b2.z+cc.z+d.z+e.z;
  v.w = a.w+b2.w+cc.w+d.w+e.w;
  float s  = v.x + v.y + v.z + v.w;
  float ss = v.x*v.x + v.y*v.y + v.z*v.z + v.w*v.w;
  #pragma unroll
  for(int m=1;m<32;m<<=1){ s += __shfl_xor(s,m,64); ss += __shfl_xor(ss,m,64); }
  float mean = s*(1.f/128.f);
  float rstd = rsqrtf(ss*(1.f/128.f) - mean*mean + 1e-5f);
  float4 gg = ((const float4*)g)[c];
  float4 bb = ((const float4*)bt)[c];
  uint2 o;
  o.x = pk2((v.x-mean)*rstd*gg.x + bb.x, (v.y-mean)*rstd*gg.y + bb.y);
  o.y = pk2((v.z-mean)*rstd*gg.z + bb.z, (v.w-mean)*rstd*gg.w + bb.w);
  ((uint2*)(outp + (size_t)row*128))[c] = o;
}

// ---------- exclusive scan of 4096 counts per (b,grouping); 16 blocks ----------
__global__ __launch_bounds__(1024) void k_scan(const int* __restrict__ cnt_all,
    int* __restrict__ offs_all, int* __restrict__ cur_all){
  int g = blockIdx.x;
  const int* src = cnt_all + g*4096;
  int* offs = offs_all + g*4097;
  int* cur  = cur_all  + g*4096;
  __shared__ int part[1024];
  int t = threadIdx.x;
  int v0=src[4*t], v1=src[4*t+1], v2=src[4*t+2], v3=src[4*t+3];
  int s = v0+v1+v2+v3;
  part[t] = s; __syncthreads();
  for(int off=1; off<1024; off<<=1){
    int x = (t>=off) ? part[t-off] : 0;
    __syncthreads();
    part[t] += x;
    __syncthreads();
  }
  int base = part[t] - s;
  offs[4*t]   = base;          cur[4*t]   = base;
  offs[4*t+1] = base+v0;       cur[4*t+1] = base+v0;
  offs[4*t+2] = base+v0+v1;    cur[4*t+2] = base+v0+v1;
  offs[4*t+3] = base+v0+v1+v2; cur[4*t+3] = base+v0+v1+v2;
  if(t==1023) offs[4096] = base+s;
}

// ---------- fill sorted point lists ----------
__global__ void k_fill(const int* __restrict__ idx_hw, const int* __restrict__ iagg,
                       int* __restrict__ cur_all, int* __restrict__ list_all){
  int tid = blockIdx.x*256 + threadIdx.x;
  int b = tid >> 14, i = tid & 16383;
  int cell = idx_hw[tid];
  int p = atomicAdd(&cur_all[b*4096 + cell], 1);
  list_all[(b<<14) + p] = i;
  int tok = iagg[tid];
  p = atomicAdd(&cur_all[(8+b)*4096 + tok], 1);
  list_all[((8+b)<<14) + p] = i;
}

// ---------- token2map for [xsn | conf]: one cell per 64-thr block, 4-point pipelined ----------
__global__ __launch_bounds__(64) void k_tmap(const u16* __restrict__ xsn, const float* __restrict__ confs,
    const int* __restrict__ iaggs, const int* __restrict__ offs_all, const int* __restrict__ list_all,
    u16* __restrict__ xs_map, float* __restrict__ conf_p){
  int b = blockIdx.x >> 12, cell = blockIdx.x & 4095;
  int lane = threadIdx.x;
  int st = offs_all[b*4097 + cell], en = offs_all[b*4097 + cell + 1];
  float a0=0.f, a1=0.f, cf=0.f;
  for(int p=st;p<en;p+=4){
    int idx[4]; float vm[4];
    #pragma unroll
    for(int j=0;j<4;j++){
      int pj = (p+j < en) ? p+j : en-1;
      vm[j] = (p+j < en) ? 1.f : 0.f;
      idx[j] = list_all[(b<<14)+pj];
    }
    int src[4];
    #pragma unroll
    for(int j=0;j<4;j++) src[j] = iaggs[(b<<14)+idx[j]];
    u32 u[4]; float cfv[4];
    #pragma unroll
    for(int j=0;j<4;j++){
      u[j]   = ((const u32*)(xsn + ((size_t)(b<<14)+src[j])*128))[lane];
      cfv[j] = confs[(b<<14)+src[j]];
    }
    #pragma unroll
    for(int j=0;j<4;j++){
      a0 += vm[j]*bf2f(u[j] & 0xffffu);
      a1 += vm[j]*bf2f(u[j] >> 16);
      cf += vm[j]*cfv[j];
    }
  }
  float inv = 1.f/fmaxf((float)(en-st), 1.f);
  ((u32*)(xs_map + ((size_t)(b<<12)+cell)*128))[lane] = pk2(a0*inv, a1*inv);
  if(lane==0){
    int ci = ((cell>>8)<<4) + ((cell&63)>>2);   // (yi/4)*16 + (xi/4)
    atomicAdd(&conf_p[b*256 + ci], cf*inv*(1.f/16.f));
  }
}

// ---------- sr-conv GEMM, split-K=4, im2col fused into A staging ----------
__global__ __launch_bounds__(256) void k_gemm_sr(const u16* __restrict__ xs_map, const u16* __restrict__ Wt,
    float* __restrict__ part){
  __shared__ __attribute__((aligned(16))) u16 lA[128*80];
  __shared__ __attribute__((aligned(16))) u16 lB[128*80];
  int m0 = blockIdx.x*128;
  int kbase = blockIdx.y*512;
  int tid = threadIdx.x, lane = tid & 63, wv = tid >> 6;
  int wm = (wv>>1)*64, wn = (wv&1)*64;
  int l16 = lane & 15, q4 = lane >> 4;
  f32x4 acc[4][4];
  for(int i=0;i<4;i++) for(int j=0;j<4;j++) acc[i][j] = (f32x4){0.f,0.f,0.f,0.f};
  for(int k0=kbase; k0<kbase+512; k0+=64){
    __syncthreads();
    for(int s=0;s<4;s++){
      int c = tid + s*256;
      int row = c >> 3, ko = (c & 7)*8;
      int m = m0 + row, k = k0 + ko;
      int b = m >> 8, oc = m & 255;
      int oy = oc >> 4, ox = oc & 15;
      int pos = k >> 7, ch = k & 127;
      int r = pos >> 2, ssp = pos & 3;
      int gy = oy*4 + r, gx = ox*4 + ssp;
      *(int4*)(lA + row*80 + ko) =
          *(const int4*)(xs_map + ((size_t)(b*4096) + gy*64 + gx)*128 + ch);
      *(int4*)(lB + row*80 + ko) = *(const int4*)(Wt + (size_t)row*2048 + k);
    }
    __syncthreads();
    for(int kk=0;kk<64;kk+=32){
      bf16x8 af[4], bfr[4];
      for(int i=0;i<4;i++) af[i]  = *(const bf16x8*)(lA + (wm + i*16 + l16)*80 + kk + q4*8);
      for(int j=0;j<4;j++) bfr[j] = *(const bf16x8*)(lB + (wn + j*16 + l16)*80 + kk + q4*8);
      for(int i=0;i<4;i++)
        for(int j=0;j<4;j++)
          acc[i][j] = MFMA16(af[i], bfr[j], acc[i][j]);
    }
  }
  float* outp = part + (size_t)blockIdx.y*262144;
  for(int i=0;i<4;i++) for(int j=0;j<4;j++){
    int col = wn + j*16 + l16;
    for(int r=0;r<4;r++){
      int row = m0 + wm + i*16 + q4*4 + r;
      outp[(size_t)row*128 + col] = acc[i][j][r];
    }
  }
}

// ---------- bf16 MFMA GEMM: out[M,N] = A[M,K] @ Wt[N,K]^T (+f32 bias)(+f32 res) ----------
__global__ __launch_bounds__(256) void k_gemm(const u16* __restrict__ Ag, const u16* __restrict__ Wt,
    const float* __restrict__ bias, const float* __restrict__ resf,
    u16* __restrict__ outb, float* __restrict__ outf, int M, int N, int K){
  __shared__ __attribute__((aligned(16))) u16 lA[128*80];
  __shared__ __attribute__((aligned(16))) u16 lB[128*80];
  int m0 = blockIdx.x*128, n0 = blockIdx.y*128;
  int tid = threadIdx.x, lane = tid & 63, wv = tid >> 6;
  int wm = (wv>>1)*64, wn = (wv&1)*64;
  int l16 = lane & 15, q4 = lane >> 4;
  f32x4 acc[4][4];
  for(int i=0;i<4;i++) for(int j=0;j<4;j++) acc[i][j] = (f32x4){0.f,0.f,0.f,0.f};
  for(int k0=0;k0<K;k0+=64){
    __syncthreads();
    for(int s=0;s<4;s++){
      int c = tid + s*256;
      int row = c >> 3, ko = (c & 7)*8;
      *(int4*)(lA + row*80 + ko) = *(const int4*)(Ag + (size_t)(m0+row)*K + k0 + ko);
      *(int4*)(lB + row*80 + ko) = *(const int4*)(Wt + (size_t)(n0+row)*K + k0 + ko);
    }
    __syncthreads();
    for(int kk=0;kk<64;kk+=32){
      bf16x8 af[4], bfr[4];
      for(int i=0;i<4;i++) af[i]  = *(const bf16x8*)(lA + (wm + i*16 + l16)*80 + kk + q4*8);
      for(int j=0;j<4;j++) bfr[j] = *(const bf16x8*)(lB + (wn + j*16 + l16)*80 + kk + q4*8);
      for(int i=0;i<4;i++)
        for(int j=0;j<4;j++)
          acc[i][j] = MFMA16(af[i], bfr[j], acc[i][j]);
    }
  }
  for(int i=0;i<4;i++) for(int j=0;j<4;j++){
    int col = n0 + wn + j*16 + l16;
    float bv = bias ? bias[col] : 0.f;
    for(int r=0;r<4;r++){
      int row = m0 + wm + i*16 + q4*4 + r;
      size_t oo = (size_t)row*N + col;
      float v = acc[i][j][r] + bv;
      if(resf) v += resf[oo];
      if(outf) outf[oo] = v;
      else     outb[oo] = f2bf(v);
    }
  }
}

// ---------- K=128 GEMM with LN fused into the A-tile prologue (A is f32, pre-LN) ----------
// Full-K LDS tiles (stride 136 u16: 16B-aligned rows, 2-way max per 16-lane phase),
// LN stats via 8-lane quad shuffles on fully-coalesced 4KB f32 loads. ONE barrier total.
__global__ __launch_bounds__(256) void k_gemm_ln(const float* __restrict__ Af,
    const float* __restrict__ g, const float* __restrict__ bt,
    const u16* __restrict__ Wt, const float* __restrict__ bias,
    u16* __restrict__ outb, int N){
  __shared__ __attribute__((aligned(16))) u16 lA[128*136];
  __shared__ __attribute__((aligned(16))) u16 lB[128*136];
  int m0 = blockIdx.x*128, n0 = blockIdx.y*128;
  int tid = threadIdx.x, lane = tid & 63, wv = tid >> 6;
  int wm = (wv>>1)*64, wn = (wv&1)*64;
  int l16 = lane & 15, q4 = lane >> 4;
  // --- A prologue: LN of 128 rows x 128 f32, 8 threads/row, 16 floats/thread ---
  {
    int p = tid & 7;
    const float4* gp = (const float4*)(g + p*16);
    const float4* bp = (const float4*)(bt + p*16);
    float4 gv[4], bv[4];
    #pragma unroll
    for(int j=0;j<4;j++){ gv[j] = gp[j]; bv[j] = bp[j]; }
    for(int grp=0; grp<4; grp++){
      int row = grp*32 + (tid>>3);
      const float4* src = (const float4*)(Af + (size_t)(m0+row)*128 + p*16);
      float4 v[4];
      #pragma unroll
      for(int j=0;j<4;j++) v[j] = src[j];
      float s = 0.f, ss = 0.f;
      #pragma unroll
      for(int j=0;j<4;j++){
        s  += v[j].x + v[j].y + v[j].z + v[j].w;
        ss += v[j].x*v[j].x + v[j].y*v[j].y + v[j].z*v[j].z + v[j].w*v[j].w;
      }
      s += __shfl_xor(s,1,64); ss += __shfl_xor(ss,1,64);
      s += __shfl_xor(s,2,64); ss += __shfl_xor(ss,2,64);
      s += __shfl_xor(s,4,64); ss += __shfl_xor(ss,4,64);
      float mean = s*(1.f/128.f);
      float rstd = rsqrtf(ss*(1.f/128.f) - mean*mean + 1e-5f);
      u32 o[8];
      #pragma unroll
      for(int j=0;j<4;j++){
        o[2*j]   = pk2((v[j].x-mean)*rstd*gv[j].x + bv[j].x, (v[j].y-mean)*rstd*gv[j].y + bv[j].y);
        o[2*j+1] = pk2((v[j].z-mean)*rstd*gv[j].z + bv[j].z, (v[j].w-mean)*rstd*gv[j].w + bv[j].w);
      }
      int4* dst = (int4*)(lA + row*136 + p*16);
      dst[0] = ((const int4*)o)[0];
      dst[1] = ((const int4*)o)[1];
    }
  }
  // --- B staging: full K=128 ---
  for(int s2=0;s2<8;s2++){
    int c = tid + s2*256;            // 0..2047
    int row = c >> 4, ko = (c & 15)*8;
    *(int4*)(lB + row*136 + ko) = *(const int4*)(Wt + (size_t)(n0+row)*128 + ko);
  }
  __syncthreads();
  // --- MFMA loop, no further barriers ---
  f32x4 acc[4][4];
  for(int i=0;i<4;i++) for(int j=0;j<4;j++) acc[i][j] = (f32x4){0.f,0.f,0.f,0.f};
  for(int kk=0;kk<128;kk+=32){
    bf16x8 af[4], bfr[4];
    for(int i=0;i<4;i++) af[i]  = *(const bf16x8*)(lA + (wm + i*16 + l16)*136 + kk + q4*8);
    for(int j=0;j<4;j++) bfr[j] = *(const bf16x8*)(lB + (wn + j*16 + l16)*136 + kk + q4*8);
    for(int i=0;i<4;i++)
      for(int j=0;j<4;j++)
        acc[i][j] = MFMA16(af[i], bfr[j], acc[i][j]);
  }
  for(int i=0;i<4;i++) for(int j=0;j<4;j++){
    int col = n0 + wn + j*16 + l16;
    float bv = bias ? bias[col] : 0.f;
    for(int r=0;r<4;r++){
      int row = m0 + wm + i*16 + q4*4 + r;
      outb[(size_t)row*N + col] = f2bf(acc[i][j][r] + bv);
    }
  }
}

// ---------- transpose V into (bh, dd, n) for PV fragment reads ----------
__global__ void k_vtrans(const u16* __restrict__ kvout, u16* __restrict__ vtg){
  int t = blockIdx.x*256 + threadIdx.x;   // 16*64*256 = 262144
  int n = t & 255, dd = (t>>8) & 63, bh = t >> 14;
  int b = bh >> 1, h = bh & 1;
  vtg[t] = kvout[((size_t)(b*256 + n))*256 + 128 + h*64 + dd];
}

// ---------- fused attention: S=QK^T*0.125+conf, softmax, O=PV ----------
__global__ __launch_bounds__(256) void k_attn(const u16* __restrict__ qb, const u16* __restrict__ kvb,
    const u16* __restrict__ vtg, const float* __restrict__ confp, u16* __restrict__ o){
  __shared__ __attribute__((aligned(16))) u16 Pl[4*16*264];
  __shared__ float cl[256];
  int bh = blockIdx.x >> 5, qblk = blockIdx.x & 31;
  int b = bh >> 1, h = bh & 1;
  int tid = threadIdx.x, lane = tid & 63, wv = tid >> 6;
  cl[tid] = confp[b*256 + tid];
  __syncthreads();
  int l16 = lane & 15, q4 = lane >> 4;
  u16* P = Pl + wv*(16*264);
  for(int it=0; it<2; it++){
    int q0 = qblk*128 + wv*32 + it*16;
    const u16* qrow = qb + ((size_t)(b*4096) + q0 + l16)*128 + h*64 + q4*8;
    bf16x8 aq0 = *(const bf16x8*)(qrow);
    bf16x8 aq1 = *(const bf16x8*)(qrow + 32);
    f32x4 sAcc[16];
    for(int nt=0; nt<16; nt++){
      const u16* krow = kvb + ((size_t)(b*256) + nt*16 + l16)*256 + h*64 + q4*8;
      bf16x8 bk0 = *(const bf16x8*)(krow);
      bf16x8 bk1 = *(const bf16x8*)(krow + 32);
      f32x4 z = (f32x4){0.f,0.f,0.f,0.f};
      z = MFMA16(aq0, bk0, z);
      z = MFMA16(aq1, bk1, z);
      sAcc[nt] = z;
    }
    float rmax[4] = {-3e38f,-3e38f,-3e38f,-3e38f};
    for(int nt=0;nt<16;nt++){
      float cb = cl[nt*16 + l16];
      for(int r=0;r<4;r++){
        float s = sAcc[nt][r]*0.125f + cb;
        sAcc[nt][r] = s;
        rmax[r] = fmaxf(rmax[r], s);
      }
    }
    for(int m=1;m<16;m<<=1)
      for(int r=0;r<4;r++) rmax[r] = fmaxf(rmax[r], __shfl_xor(rmax[r], m, 64));
    float rsum[4] = {0.f,0.f,0.f,0.f};
    for(int nt=0;nt<16;nt++)
      for(int r=0;r<4;r++){ float p = __expf(sAcc[nt][r]-rmax[r]); sAcc[nt][r]=p; rsum[r]+=p; }
    for(int m=1;m<16;m<<=1)
      for(int r=0;r<4;r++) rsum[r] += __shfl_xor(rsum[r], m, 64);
    for(int nt=0;nt<16;nt++)
      for(int r=0;r<4;r++) P[(q4*4+r)*264 + nt*16 + l16] = f2bf(sAcc[nt][r]);
    __syncthreads();
    f32x4 oAcc[4];
    for(int dt=0;dt<4;dt++) oAcc[dt] = (f32x4){0.f,0.f,0.f,0.f};
    for(int kc=0;kc<8;kc++){
      bf16x8 ap = *(const bf16x8*)(P + l16*264 + kc*32 + q4*8);
      for(int dt=0; dt<4; dt++){
        const u16* vrow = vtg + ((size_t)(bh*64) + dt*16 + l16)*256 + kc*32 + q4*8;
        bf16x8 bv = *(const bf16x8*)(vrow);
        oAcc[dt] = MFMA16(ap, bv, oAcc[dt]);
      }
    }
    float rinv[4]; for(int r=0;r<4;r++) rinv[r] = 1.f/rsum[r];
    for(int dt=0;dt<4;dt++)
      for(int r=0;r<4;r++){
        int row = q0 + q4*4 + r, col = h*64 + dt*16 + l16;
        o[((size_t)(b*4096)+row)*128 + col] = f2bf(oAcc[dt][r]*rinv[r]);
      }
    __syncthreads();
  }
}

// ---------- token2map for h (512 ch): one cell per 128-thr block, 4-point pipelined ----------
__global__ __launch_bounds__(128) void k_hmap(const u16* __restrict__ hsrc, const int* __restrict__ iagg,
    const int* __restrict__ offs_all, const int* __restrict__ list_all, u16* __restrict__ hmap){
  int b = blockIdx.x >> 12, cell = blockIdx.x & 4095;
  int c0 = threadIdx.x*4;
  int st = offs_all[b*4097+cell], en = offs_all[b*4097+cell+1];
  float a0=0.f,a1=0.f,a2=0.f,a3=0.f;
  for(int p=st;p<en;p+=4){
    int idx[4]; float vm[4];
    #pragma unroll
    for(int j=0;j<4;j++){
      int pj = (p+j < en) ? p+j : en-1;
      vm[j] = (p+j < en) ? 1.f : 0.f;
      idx[j] = list_all[(b<<14)+pj];
    }
    int src[4];
    #pragma unroll
    for(int j=0;j<4;j++) src[j] = iagg[(b<<14)+idx[j]];
    uint2 u[4];
    #pragma unroll
    for(int j=0;j<4;j++) u[j] = *(const uint2*)(hsrc + ((size_t)(b<<12)+src[j])*512 + c0);
    #pragma unroll
    for(int j=0;j<4;j++){
      a0 += vm[j]*bf2f(u[j].x & 0xffffu); a1 += vm[j]*bf2f(u[j].x >> 16);
      a2 += vm[j]*bf2f(u[j].y & 0xffffu); a3 += vm[j]*bf2f(u[j].y >> 16);
    }
  }
  float inv = 1.f/fmaxf((float)(en-st), 1.f);
  uint2 o; o.x = pk2(a0*inv, a1*inv); o.y = pk2(a2*inv, a3*inv);
  *(uint2*)(hmap + ((size_t)(b<<12)+cell)*512 + c0) = o;
}

// ---------- 3x3 SAME depthwise conv + bias: 4 x-positions x 4 channels per thread ----------
__global__ __launch_bounds__(256) void k_dw(const u16* __restrict__ hmap, const float* __restrict__ dww,
    const float* __restrict__ dwb, u16* __restrict__ outm){
  int g = blockIdx.x*256 + threadIdx.x;   // 1,048,576 threads
  int cq = g & 127;
  int xg = (g>>7) & 15;
  int yy = (g>>11) & 63;
  int b  = g >> 17;
  int c0 = cq*4;
  int x0 = xg*4;
  float4 bb = *(const float4*)(dwb + c0);
  float acc[4][4];
  for(int xo=0;xo<4;xo++){ acc[xo][0]=bb.x; acc[xo][1]=bb.y; acc[xo][2]=bb.z; acc[xo][3]=bb.w; }
  for(int r=0;r<3;r++){
    int ys = yy + r - 1;
    if(ys < 0 || ys > 63) continue;            // zero padding rows
    const u16* rp = hmap + ((size_t)((b<<12) + ys*64))*512;
    float col[6][4];
    for(int cc=0;cc<6;cc++){
      int xx = x0 + cc - 1;
      uint2 u = make_uint2(0u,0u);
      if(xx >= 0 && xx <= 63) u = *(const uint2*)(rp + (size_t)xx*512 + c0);
      col[cc][0]=bf2f(u.x&0xffffu); col[cc][1]=bf2f(u.x>>16);
      col[cc][2]=bf2f(u.y&0xffffu); col[cc][3]=bf2f(u.y>>16);
    }
    for(int s=0;s<3;s++){
      float4 wv = *(const float4*)(dww + (r*3+s)*512 + c0);
      for(int xo=0;xo<4;xo++){
        acc[xo][0] += wv.x*col[xo+s][0];
        acc[xo][1] += wv.y*col[xo+s][1];
        acc[xo][2] += wv.z*col[xo+s][2];
        acc[xo][3] += wv.w*col[xo+s][3];
      }
    }
  }
  for(int xo=0;xo<4;xo++){
    int pos = (b<<12) + yy*64 + x0 + xo;
    uint2 o; o.x = pk2(acc[xo][0],acc[xo][1]); o.y = pk2(acc[xo][2],acc[xo][3]);
    *(uint2*)(outm + (size_t)pos*512 + c0) = o;
  }
}

// ---------- map2token + dwskip + GELU: one token per 128-thr block, 4-point pipelined ----------
__global__ __launch_bounds__(128) void k_m2t(const u16* __restrict__ hdw, const u16* __restrict__ hbuf,
    const float* __restrict__ aggw, const int* __restrict__ idx_hw, const int* __restrict__ offs_all,
    const int* __restrict__ list_all, const float* __restrict__ dwskip, u16* __restrict__ ht){
  int b = blockIdx.x >> 12, tok = blockIdx.x & 4095;
  int c0 = threadIdx.x*4;
  int st = offs_all[(8+b)*4097+tok], en = offs_all[(8+b)*4097+tok+1];
  float n0=0.f,n1=0.f,n2=0.f,n3=0.f,den=0.f;
  for(int p=st;p<en;p+=4){
    int idx[4]; float vm[4];
    #pragma unroll
    for(int j=0;j<4;j++){
      int pj = (p+j < en) ? p+j : en-1;
      vm[j] = (p+j < en) ? 1.f : 0.f;
      idx[j] = list_all[((8+b)<<14)+pj];
    }
    float w[4]; int cell[4];
    #pragma unroll
    for(int j=0;j<4;j++){
      w[j] = vm[j]*aggw[(b<<14)+idx[j]];
      cell[j] = idx_hw[(b<<14)+idx[j]];
    }
    uint2 u[4];
    #pragma unroll
    for(int j=0;j<4;j++) u[j] = *(const uint2*)(hdw + ((size_t)(b<<12)+cell[j])*512 + c0);
    #pragma unroll
    for(int j=0;j<4;j++){
      n0 += w[j]*bf2f(u[j].x & 0xffffu); n1 += w[j]*bf2f(u[j].x >> 16);
      n2 += w[j]*bf2f(u[j].y & 0xffffu); n3 += w[j]*bf2f(u[j].y >> 16);
      den += w[j];
    }
  }
  float inv = 1.f/fmaxf(den, 1e-6f);
  uint2 hu = *(const uint2*)(hbuf + ((size_t)(b<<12)+tok)*512 + c0);
  float4 sk = *(const float4*)(dwskip + c0);
  float v0 = geluf(n0*inv + bf2f(hu.x&0xffffu)*sk.x);
  float v1 = geluf(n1*inv + bf2f(hu.x>>16)   *sk.y);
  float v2 = geluf(n2*inv + bf2f(hu.y&0xffffu)*sk.z);
  float v3 = geluf(n3*inv + bf2f(hu.y>>16)   *sk.w);
  uint2 o; o.x=pk2(v0,v1); o.y=pk2(v2,v3);
  *(uint2*)(ht + ((size_t)(b<<12)+tok)*512 + c0) = o;
}

extern "C" void kernel_launch(void* const* d_in, const int* in_sizes, int n_in,
                              void* d_out, int out_size, void* d_ws, size_t ws_size,
                              hipStream_t stream){
  (void)in_sizes; (void)n_in; (void)out_size; (void)ws_size;
  const float* x     = (const float*)d_in[0];
  const float* loc   = (const float*)d_in[1];
  const int*   iagg  = (const int*)d_in[2];
  const float* aggw  = (const float*)d_in[3];
  const float* xsrc  = (const float*)d_in[4];
  const int*   iaggs = (const int*)d_in[5];
  const float* confs = (const float*)d_in[6];
  const float* ln1g  = (const float*)d_in[7];
  const float* ln1b  = (const float*)d_in[8];
  const float* ln2g  = (const float*)d_in[9];
  const float* ln2b  = (const float*)d_in[10];
  const float* wq    = (const float*)d_in[11];
  const float* wkv   = (const float*)d_in[12];
  const float* wproj = (const float*)d_in[13];
  const float* bproj = (const float*)d_in[14];
  const float* srw   = (const float*)d_in[15];
  const float* srb   = (const float*)d_in[16];
  const float* srng  = (const float*)d_in[17];
  const float* srnb  = (const float*)d_in[18];
  const float* fc1w  = (const float*)d_in[19];
  const float* fc1b  = (const float*)d_in[20];
  const float* dww   = (const float*)d_in[21];
  const float* dwb   = (const float*)d_in[22];
  const float* dwskip= (const float*)d_in[23];
  const float* fc2w  = (const float*)d_in[24];
  const float* fc2b  = (const float*)d_in[25];
  float* out = (float*)d_out;

  char* ws = (char*)d_ws;
  size_t off = 0;
  auto A = [&](size_t n)->char*{ char* p = ws + off; off = (off + n + 255) & ~(size_t)255; return p; };
  // ---- zeroed block (cnt_all + conf_p contiguous; one memset) ----
  int*   cnt_all  = (int*)A(16*4096*4);
  float* conf_p   = (float*)A(8*256*4);
  // ---- small region ----
  int*   offs_all = (int*)A(16*4097*4);
  int*   cur_all  = (int*)A(16*4096*4);
  int*   list_all = (int*)A(16*16384*4);
  int*   idx_hw   = (int*)A(8*16384*4);
  u16* wqT    = (u16*)A(128*128*2);
  u16* wkvT   = (u16*)A(256*128*2);
  u16* wprojT = (u16*)A(128*128*2);
  u16* fc1T   = (u16*)A(512*128*2);
  u16* fc2T   = (u16*)A(128*512*2);
  u16* srwT   = (u16*)A(128*2048*2);
  // ---- big regions with explicit overlays (lifetimes verified disjoint) ----
  char* R0 = A(33554432);   // 32MB: xsn (dead after k_tmap) -> hbuf (fc1 out)
  char* R1 = A(33554432);   // 32MB: hmap (dead after k_dw) -> ht (m2t out)
  char* R2 = A(33554432);   // 32MB: {attn_o, qout, xs_part, kvout, vtg, xs} -> hdw
  char* R3 = A(8388608);    //  8MB: xs_map
  char* R4 = A(16777216);   // 16MB: x1 (float, lives to end)
  u16* xsn    = (u16*)R0;  u16* hbuf = (u16*)R0;
  u16* hmap   = (u16*)R1;  u16* ht   = (u16*)R1;
  u16* attn_o = (u16*)R2;
  u16* qout   = (u16*)(R2 + 8388608);
  float* xs_part = (float*)(R2 + 16777216);
  u16* kvout  = (u16*)(R2 + 25165824);
  u16* vtg    = (u16*)(R2 + 26214400);
  u16* xs     = (u16*)(R2 + 27262976);
  u16* hdw    = (u16*)R2;
  u16* xs_map = (u16*)R3;
  float* x1   = (float*)R4;

  hipMemsetAsync(cnt_all, 0, 16*4096*4 + 8*256*4, stream);

  k_prep<<<dim3(2304), 256, 0, stream>>>(wq, wqT, wkv, wkvT, wproj, wprojT,
      fc1w, fc1T, fc2w, fc2T, srw, srwT, loc, iagg, idx_hw, cnt_all);

  k_ln1<<<dim3(16384), 256, 0, stream>>>(xsrc, xsn, ln1g, ln1b);

  k_scan<<<dim3(16), 1024, 0, stream>>>(cnt_all, offs_all, cur_all);
  k_fill<<<dim3(512), 256, 0, stream>>>(idx_hw, iagg, cur_all, list_all);

  k_tmap<<<dim3(32768), 64, 0, stream>>>(xsn, confs, iaggs, offs_all, list_all, xs_map, conf_p);

  k_gemm_sr<<<dim3(16,4), 256, 0, stream>>>(xs_map, srwT, xs_part);
  k_ln_sr<<<dim3(256), 256, 0, stream>>>(xs_part, srb, srng, srnb, xs);

  k_gemm_ln<<<dim3(256,1), 256, 0, stream>>>(x, ln1g, ln1b, wqT, nullptr, qout, 128);
  k_gemm<<<dim3(16,2),  256, 0, stream>>>(xs, wkvT, nullptr, nullptr, kvout, nullptr, 2048, 256, 128);
  k_vtrans<<<dim3(1024), 256, 0, stream>>>(kvout, vtg);

  k_attn<<<dim3(512), 256, 0, stream>>>(qout, kvout, vtg, conf_p, attn_o);

  k_gemm<<<dim3(256,1), 256, 0, stream>>>(attn_o, wprojT, bproj, x, nullptr, x1, 32768, 128, 128);
  k_gemm_ln<<<dim3(256,4), 256, 0, stream>>>(x1, ln2g, ln2b, fc1T, fc1b, hbuf, 512);

  k_hmap<<<dim3(32768), 128, 0, stream>>>(hbuf, iagg, offs_all, list_all, hmap);
  k_dw<<<dim3(4096), 256, 0, stream>>>(hmap, dww, dwb, hdw);
  k_m2t<<<dim3(32768), 128, 0, stream>>>(hdw, hbuf, aggw, idx_hw, offs_all, list_all, dwskip, ht);

  k_gemm<<<dim3(256,1), 256, 0, stream>>>(ht, fc2T, fc2b, x1, nullptr, out, 32768, 128, 512);
}

// Round 8
// 435.178 us; speedup vs baseline: 1.2070x; 1.0184x over previous
//
#include <hip/hip_runtime.h>

typedef unsigned short u16;
typedef unsigned int   u32;
typedef short bf16x8 __attribute__((ext_vector_type(8)));
typedef float f32x4  __attribute__((ext_vector_type(4)));

#define MFMA16(a,b,c) __builtin_amdgcn_mfma_f32_16x16x32_bf16((a),(b),(c),0,0,0)

// ---------- bf16 helpers (storage = u16, compute = f32) ----------
__device__ __forceinline__ float bf2f(u32 u){ union{u32 i; float f;} v; v.i = u<<16; return v.f; }
__device__ __forceinline__ u16 f2bf(float f){
  union{float f; u32 i;} v; v.f=f; u32 i=v.i;
  return (u16)((i + 0x7fffu + ((i>>16)&1u)) >> 16);   // round-nearest-even
}
__device__ __forceinline__ u32 pk2(float a, float b){ return (u32)f2bf(a) | ((u32)f2bf(b)<<16); }
__device__ __forceinline__ float geluf(float x){ return 0.5f*x*(1.f + erff(x*0.7071067811865475f)); }

// ---------- fused prep: LN(xsrc) [blocks 0..16383] + 6 weight transposes + hist ----------
__global__ __launch_bounds__(256) void k_prep(const float* __restrict__ wq, u16* __restrict__ wqT,
                       const float* __restrict__ wkv, u16* __restrict__ wkvT,
                       const float* __restrict__ wproj, u16* __restrict__ wprojT,
                       const float* __restrict__ fc1w, u16* __restrict__ fc1T,
                       const float* __restrict__ fc2w, u16* __restrict__ fc2T,
                       const float* __restrict__ srw, u16* __restrict__ srwT,
                       const float* __restrict__ loc, const int* __restrict__ iagg,
                       int* __restrict__ idx_hw, int* __restrict__ cnt_all,
                       const float* __restrict__ xsrc, u16* __restrict__ xsn,
                       const float* __restrict__ g, const float* __restrict__ bt){
  if(blockIdx.x < 16384){
    // LN of xsrc: half-wave per row, fully coalesced
    int t = blockIdx.x*256 + threadIdx.x;
    int row = t >> 5, c = t & 31;
    float4 v = ((const float4*)(xsrc + (size_t)row*128))[c];
    float s  = v.x + v.y + v.z + v.w;
    float ss = v.x*v.x + v.y*v.y + v.z*v.z + v.w*v.w;
    #pragma unroll
    for(int m=1;m<32;m<<=1){ s += __shfl_xor(s,m,64); ss += __shfl_xor(ss,m,64); }
    float mean = s*(1.f/128.f);
    float rstd = rsqrtf(ss*(1.f/128.f) - mean*mean + 1e-5f);
    float4 gg = ((const float4*)g)[c];
    float4 bb = ((const float4*)bt)[c];
    uint2 o;
    o.x = pk2((v.x-mean)*rstd*gg.x + bb.x, (v.y-mean)*rstd*gg.y + bb.y);
    o.y = pk2((v.z-mean)*rstd*gg.z + bb.z, (v.w-mean)*rstd*gg.w + bb.w);
    ((uint2*)(xsn + (size_t)row*128))[c] = o;
    return;
  }
  int t = (blockIdx.x-16384)*256 + threadIdx.x;
  if(t < 458752){
    const float* w; u16* wt; int li, Nsh, K;
    if(t < 16384){ w=wq; wt=wqT; li=t; Nsh=7; K=128; }
    else if(t < 49152){ w=wkv; wt=wkvT; li=t-16384; Nsh=8; K=128; }
    else if(t < 65536){ w=wproj; wt=wprojT; li=t-49152; Nsh=7; K=128; }
    else if(t < 131072){ w=fc1w; wt=fc1T; li=t-65536; Nsh=9; K=128; }
    else if(t < 196608){ w=fc2w; wt=fc2T; li=t-131072; Nsh=7; K=512; }
    else { w=srw; wt=srwT; li=t-196608; Nsh=7; K=2048; }
    int k = li >> Nsh, n = li & ((1<<Nsh)-1);
    wt[(size_t)n*K + k] = f2bf(w[li]);
  } else {
    int tid = t - 458752;          // 0..131071
    int b = tid >> 14;
    float lx = loc[(size_t)tid*2];
    float ly = loc[(size_t)tid*2+1];
    float tx = (fminf(fmaxf(lx,-1.f),1.f)+1.f)*0.5f;
    float ty = (fminf(fmaxf(ly,-1.f),1.f)+1.f)*0.5f;
    int xi = (int)rintf(tx*63.f);   // round-half-even, matches jnp.round
    int yi = (int)rintf(ty*63.f);
    int cell = yi*64 + xi;
    idx_hw[tid] = cell;
    atomicAdd(&cnt_all[b*4096 + cell], 1);
    atomicAdd(&cnt_all[(8+b)*4096 + iagg[tid]], 1);
  }
}

// ---------- LN over sum of 4 split-K partials + conv bias ----------
__global__ __launch_bounds__(256) void k_ln_sr(const float* __restrict__ part, const float* __restrict__ srb,
    const float* __restrict__ g, const float* __restrict__ bt, u16* __restrict__ outp){
  int t = blockIdx.x*256 + threadIdx.x;     // 2048 rows * 32 = 65536 threads
  int row = t >> 5, c = t & 31;
  const float4* p0 = (const float4*)(part +           (size_t)row*128);
  const float4* p1 = (const float4*)(part + 262144 +  (size_t)row*128);
  const float4* p2 = (const float4*)(part + 524288 +  (size_t)row*128);
  const float4* p3 = (const float4*)(part + 786432 +  (size_t)row*128);
  float4 a = p0[c], b2 = p1[c], cc = p2[c], d = p3[c];
  float4 e = ((const float4*)srb)[c];
  float4 v;
  v.x = a.x+b2.x+cc.x+d.x+e.x;
  v.y = a.y+b2.y+cc.y+d.y+e.y;
  v.z = a.z+b2.z+cc.z+d.z+e.z;
  v.w = a.w+b2.w+cc.w+d.w+e.w;
  float s  = v.x + v.y + v.z + v.w;
  float ss = v.x*v.x + v.y*v.y + v.z*v.z + v.w*v.w;
  #pragma unroll
  for(int m=1;m<32;m<<=1){ s += __shfl_xor(s,m,64); ss += __shfl_xor(ss,m,64); }
  float mean = s*(1.f/128.f);
  float rstd = rsqrtf(ss*(1.f/128.f) - mean*mean + 1e-5f);
  float4 gg = ((const float4*)g)[c];
  float4 bb = ((const float4*)bt)[c];
  uint2 o;
  o.x = pk2((v.x-mean)*rstd*gg.x + bb.x, (v.y-mean)*rstd*gg.y + bb.y);
  o.y = pk2((v.z-mean)*rstd*gg.z + bb.z, (v.w-mean)*rstd*gg.w + bb.w);
  ((uint2*)(outp + (size_t)row*128))[c] = o;
}

// ---------- exclusive scan of 4096 counts per (b,grouping); 16 blocks ----------
__global__ __launch_bounds__(1024) void k_scan(const int* __restrict__ cnt_all,
    int* __restrict__ offs_all, int* __restrict__ cur_all){
  int g = blockIdx.x;
  const int* src = cnt_all + g*4096;
  int* offs = offs_all + g*4097;
  int* cur  = cur_all  + g*4096;
  __shared__ int part[1024];
  int t = threadIdx.x;
  int v0=src[4*t], v1=src[4*t+1], v2=src[4*t+2], v3=src[4*t+3];
  int s = v0+v1+v2+v3;
  part[t] = s; __syncthreads();
  for(int off=1; off<1024; off<<=1){
    int x = (t>=off) ? part[t-off] : 0;
    __syncthreads();
    part[t] += x;
    __syncthreads();
  }
  int base = part[t] - s;
  offs[4*t]   = base;          cur[4*t]   = base;
  offs[4*t+1] = base+v0;       cur[4*t+1] = base+v0;
  offs[4*t+2] = base+v0+v1;    cur[4*t+2] = base+v0+v1;
  offs[4*t+3] = base+v0+v1+v2; cur[4*t+3] = base+v0+v1+v2;
  if(t==1023) offs[4096] = base+s;
}

// ---------- fill sorted point lists ----------
__global__ void k_fill(const int* __restrict__ idx_hw, const int* __restrict__ iagg,
                       int* __restrict__ cur_all, int* __restrict__ list_all){
  int tid = blockIdx.x*256 + threadIdx.x;
  int b = tid >> 14, i = tid & 16383;
  int cell = idx_hw[tid];
  int p = atomicAdd(&cur_all[b*4096 + cell], 1);
  list_all[(b<<14) + p] = i;
  int tok = iagg[tid];
  p = atomicAdd(&cur_all[(8+b)*4096 + tok], 1);
  list_all[((8+b)<<14) + p] = i;
}

// ---------- token2map for [xsn | conf]: one cell per 64-thr block, 4-point pipelined ----------
__global__ __launch_bounds__(64) void k_tmap(const u16* __restrict__ xsn, const float* __restrict__ confs,
    const int* __restrict__ iaggs, const int* __restrict__ offs_all, const int* __restrict__ list_all,
    u16* __restrict__ xs_map, float* __restrict__ conf_p){
  int b = blockIdx.x >> 12, cell = blockIdx.x & 4095;
  int lane = threadIdx.x;
  int st = offs_all[b*4097 + cell], en = offs_all[b*4097 + cell + 1];
  float a0=0.f, a1=0.f, cf=0.f;
  for(int p=st;p<en;p+=4){
    int idx[4]; float vm[4];
    #pragma unroll
    for(int j=0;j<4;j++){
      int pj = (p+j < en) ? p+j : en-1;
      vm[j] = (p+j < en) ? 1.f : 0.f;
      idx[j] = list_all[(b<<14)+pj];
    }
    int src[4];
    #pragma unroll
    for(int j=0;j<4;j++) src[j] = iaggs[(b<<14)+idx[j]];
    u32 u[4]; float cfv[4];
    #pragma unroll
    for(int j=0;j<4;j++){
      u[j]   = ((const u32*)(xsn + ((size_t)(b<<14)+src[j])*128))[lane];
      cfv[j] = confs[(b<<14)+src[j]];
    }
    #pragma unroll
    for(int j=0;j<4;j++){
      a0 += vm[j]*bf2f(u[j] & 0xffffu);
      a1 += vm[j]*bf2f(u[j] >> 16);
      cf += vm[j]*cfv[j];
    }
  }
  float inv = 1.f/fmaxf((float)(en-st), 1.f);
  ((u32*)(xs_map + ((size_t)(b<<12)+cell)*128))[lane] = pk2(a0*inv, a1*inv);
  if(lane==0){
    int ci = ((cell>>8)<<4) + ((cell&63)>>2);   // (yi/4)*16 + (xi/4)
    atomicAdd(&conf_p[b*256 + ci], cf*inv*(1.f/16.f));
  }
}

// ---------- sr-conv GEMM, split-K=4, im2col fused into A staging ----------
__global__ __launch_bounds__(256) void k_gemm_sr(const u16* __restrict__ xs_map, const u16* __restrict__ Wt,
    float* __restrict__ part){
  __shared__ __attribute__((aligned(16))) u16 lA[128*80];
  __shared__ __attribute__((aligned(16))) u16 lB[128*80];
  int m0 = blockIdx.x*128;
  int kbase = blockIdx.y*512;
  int tid = threadIdx.x, lane = tid & 63, wv = tid >> 6;
  int wm = (wv>>1)*64, wn = (wv&1)*64;
  int l16 = lane & 15, q4 = lane >> 4;
  f32x4 acc[4][4];
  for(int i=0;i<4;i++) for(int j=0;j<4;j++) acc[i][j] = (f32x4){0.f,0.f,0.f,0.f};
  for(int k0=kbase; k0<kbase+512; k0+=64){
    __syncthreads();
    for(int s=0;s<4;s++){
      int c = tid + s*256;
      int row = c >> 3, ko = (c & 7)*8;
      int m = m0 + row, k = k0 + ko;
      int b = m >> 8, oc = m & 255;
      int oy = oc >> 4, ox = oc & 15;
      int pos = k >> 7, ch = k & 127;
      int r = pos >> 2, ssp = pos & 3;
      int gy = oy*4 + r, gx = ox*4 + ssp;
      *(int4*)(lA + row*80 + ko) =
          *(const int4*)(xs_map + ((size_t)(b*4096) + gy*64 + gx)*128 + ch);
      *(int4*)(lB + row*80 + ko) = *(const int4*)(Wt + (size_t)row*2048 + k);
    }
    __syncthreads();
    for(int kk=0;kk<64;kk+=32){
      bf16x8 af[4], bfr[4];
      for(int i=0;i<4;i++) af[i]  = *(const bf16x8*)(lA + (wm + i*16 + l16)*80 + kk + q4*8);
      for(int j=0;j<4;j++) bfr[j] = *(const bf16x8*)(lB + (wn + j*16 + l16)*80 + kk + q4*8);
      for(int i=0;i<4;i++)
        for(int j=0;j<4;j++)
          acc[i][j] = MFMA16(af[i], bfr[j], acc[i][j]);
    }
  }
  float* outp = part + (size_t)blockIdx.y*262144;
  for(int i=0;i<4;i++) for(int j=0;j<4;j++){
    int col = wn + j*16 + l16;
    for(int r=0;r<4;r++){
      int row = m0 + wm + i*16 + q4*4 + r;
      outp[(size_t)row*128 + col] = acc[i][j][r];
    }
  }
}

// ---------- bf16 MFMA GEMM, 64x128 tile (2 blocks/CU at M=32768): ----------
// out[M,N] = A[M,K] @ Wt[N,K]^T (+f32 bias)(+f32 res); optional fused V-transpose (vtg)
__global__ __launch_bounds__(256) void k_gemm(const u16* __restrict__ Ag, const u16* __restrict__ Wt,
    const float* __restrict__ bias, const float* __restrict__ resf,
    u16* __restrict__ outb, float* __restrict__ outf, u16* __restrict__ vtg,
    int M, int N, int K){
  __shared__ __attribute__((aligned(16))) u16 lA[64*80];
  __shared__ __attribute__((aligned(16))) u16 lB[128*80];
  int m0 = blockIdx.x*64, n0 = blockIdx.y*128;
  int tid = threadIdx.x, lane = tid & 63, wv = tid >> 6;
  int wm = (wv>>1)*32, wn = (wv&1)*64;
  int l16 = lane & 15, q4 = lane >> 4;
  f32x4 acc[2][4];
  for(int i=0;i<2;i++) for(int j=0;j<4;j++) acc[i][j] = (f32x4){0.f,0.f,0.f,0.f};
  for(int k0=0;k0<K;k0+=64){
    __syncthreads();
    for(int s=0;s<2;s++){
      int c = tid + s*256;
      int row = c >> 3, ko = (c & 7)*8;
      *(int4*)(lA + row*80 + ko) = *(const int4*)(Ag + (size_t)(m0+row)*K + k0 + ko);
    }
    for(int s=0;s<4;s++){
      int c = tid + s*256;
      int row = c >> 3, ko = (c & 7)*8;
      *(int4*)(lB + row*80 + ko) = *(const int4*)(Wt + (size_t)(n0+row)*K + k0 + ko);
    }
    __syncthreads();
    for(int kk=0;kk<64;kk+=32){
      bf16x8 af[2], bfr[4];
      for(int i=0;i<2;i++) af[i]  = *(const bf16x8*)(lA + (wm + i*16 + l16)*80 + kk + q4*8);
      for(int j=0;j<4;j++) bfr[j] = *(const bf16x8*)(lB + (wn + j*16 + l16)*80 + kk + q4*8);
      for(int i=0;i<2;i++)
        for(int j=0;j<4;j++)
          acc[i][j] = MFMA16(af[i], bfr[j], acc[i][j]);
    }
  }
  for(int i=0;i<2;i++) for(int j=0;j<4;j++){
    int col = n0 + wn + j*16 + l16;
    float bv = bias ? bias[col] : 0.f;
    for(int r=0;r<4;r++){
      int row = m0 + wm + i*16 + q4*4 + r;
      size_t oo = (size_t)row*N + col;
      float v = acc[i][j][r] + bv;
      if(resf) v += resf[oo];
      u16 bfv = f2bf(v);
      if(outf) outf[oo] = v;
      else     outb[oo] = bfv;
      if(vtg && col >= 128){     // kv GEMM: scatter V into (bh, dd, n) layout
        int h = (col-128) >> 6, dd = (col-128) & 63;
        int bb2 = row >> 8, nn = row & 255;
        vtg[(((size_t)(bb2*2+h)*64 + dd) << 8) + nn] = bfv;
      }
    }
  }
}

// ---------- K=128 GEMM with LN fused into the A-tile prologue (A is f32, pre-LN) ----------
__global__ __launch_bounds__(256) void k_gemm_ln(const float* __restrict__ Af,
    const float* __restrict__ g, const float* __restrict__ bt,
    const u16* __restrict__ Wt, const float* __restrict__ bias,
    u16* __restrict__ outb, int N){
  __shared__ __attribute__((aligned(16))) u16 lA[128*136];
  __shared__ __attribute__((aligned(16))) u16 lB[128*136];
  int m0 = blockIdx.x*128, n0 = blockIdx.y*128;
  int tid = threadIdx.x, lane = tid & 63, wv = tid >> 6;
  int wm = (wv>>1)*64, wn = (wv&1)*64;
  int l16 = lane & 15, q4 = lane >> 4;
  {
    int p = tid & 7;
    const float4* gp = (const float4*)(g + p*16);
    const float4* bp = (const float4*)(bt + p*16);
    float4 gv[4], bv[4];
    #pragma unroll
    for(int j=0;j<4;j++){ gv[j] = gp[j]; bv[j] = bp[j]; }
    for(int grp=0; grp<4; grp++){
      int row = grp*32 + (tid>>3);
      const float4* src = (const float4*)(Af + (size_t)(m0+row)*128 + p*16);
      float4 v[4];
      #pragma unroll
      for(int j=0;j<4;j++) v[j] = src[j];
      float s = 0.f, ss = 0.f;
      #pragma unroll
      for(int j=0;j<4;j++){
        s  += v[j].x + v[j].y + v[j].z + v[j].w;
        ss += v[j].x*v[j].x + v[j].y*v[j].y + v[j].z*v[j].z + v[j].w*v[j].w;
      }
      s += __shfl_xor(s,1,64); ss += __shfl_xor(ss,1,64);
      s += __shfl_xor(s,2,64); ss += __shfl_xor(ss,2,64);
      s += __shfl_xor(s,4,64); ss += __shfl_xor(ss,4,64);
      float mean = s*(1.f/128.f);
      float rstd = rsqrtf(ss*(1.f/128.f) - mean*mean + 1e-5f);
      u32 o[8];
      #pragma unroll
      for(int j=0;j<4;j++){
        o[2*j]   = pk2((v[j].x-mean)*rstd*gv[j].x + bv[j].x, (v[j].y-mean)*rstd*gv[j].y + bv[j].y);
        o[2*j+1] = pk2((v[j].z-mean)*rstd*gv[j].z + bv[j].z, (v[j].w-mean)*rstd*gv[j].w + bv[j].w);
      }
      int4* dst = (int4*)(lA + row*136 + p*16);
      dst[0] = ((const int4*)o)[0];
      dst[1] = ((const int4*)o)[1];
    }
  }
  for(int s2=0;s2<8;s2++){
    int c = tid + s2*256;            // 0..2047
    int row = c >> 4, ko = (c & 15)*8;
    *(int4*)(lB + row*136 + ko) = *(const int4*)(Wt + (size_t)(n0+row)*128 + ko);
  }
  __syncthreads();
  f32x4 acc[4][4];
  for(int i=0;i<4;i++) for(int j=0;j<4;j++) acc[i][j] = (f32x4){0.f,0.f,0.f,0.f};
  for(int kk=0;kk<128;kk+=32){
    bf16x8 af[4], bfr[4];
    for(int i=0;i<4;i++) af[i]  = *(const bf16x8*)(lA + (wm + i*16 + l16)*136 + kk + q4*8);
    for(int j=0;j<4;j++) bfr[j] = *(const bf16x8*)(lB + (wn + j*16 + l16)*136 + kk + q4*8);
    for(int i=0;i<4;i++)
      for(int j=0;j<4;j++)
        acc[i][j] = MFMA16(af[i], bfr[j], acc[i][j]);
  }
  for(int i=0;i<4;i++) for(int j=0;j<4;j++){
    int col = n0 + wn + j*16 + l16;
    float bv = bias ? bias[col] : 0.f;
    for(int r=0;r<4;r++){
      int row = m0 + wm + i*16 + q4*4 + r;
      outb[(size_t)row*N + col] = f2bf(acc[i][j][r] + bv);
    }
  }
}

// ---------- fused attention: S=QK^T*0.125+conf, softmax, O=PV ----------
__global__ __launch_bounds__(256) void k_attn(const u16* __restrict__ qb, const u16* __restrict__ kvb,
    const u16* __restrict__ vtg, const float* __restrict__ confp, u16* __restrict__ o){
  __shared__ __attribute__((aligned(16))) u16 Pl[4*16*264];
  __shared__ float cl[256];
  int bh = blockIdx.x >> 5, qblk = blockIdx.x & 31;
  int b = bh >> 1, h = bh & 1;
  int tid = threadIdx.x, lane = tid & 63, wv = tid >> 6;
  cl[tid] = confp[b*256 + tid];
  __syncthreads();
  int l16 = lane & 15, q4 = lane >> 4;
  u16* P = Pl + wv*(16*264);
  for(int it=0; it<2; it++){
    int q0 = qblk*128 + wv*32 + it*16;
    const u16* qrow = qb + ((size_t)(b*4096) + q0 + l16)*128 + h*64 + q4*8;
    bf16x8 aq0 = *(const bf16x8*)(qrow);
    bf16x8 aq1 = *(const bf16x8*)(qrow + 32);
    f32x4 sAcc[16];
    for(int nt=0; nt<16; nt++){
      const u16* krow = kvb + ((size_t)(b*256) + nt*16 + l16)*256 + h*64 + q4*8;
      bf16x8 bk0 = *(const bf16x8*)(krow);
      bf16x8 bk1 = *(const bf16x8*)(krow + 32);
      f32x4 z = (f32x4){0.f,0.f,0.f,0.f};
      z = MFMA16(aq0, bk0, z);
      z = MFMA16(aq1, bk1, z);
      sAcc[nt] = z;
    }
    float rmax[4] = {-3e38f,-3e38f,-3e38f,-3e38f};
    for(int nt=0;nt<16;nt++){
      float cb = cl[nt*16 + l16];
      for(int r=0;r<4;r++){
        float s = sAcc[nt][r]*0.125f + cb;
        sAcc[nt][r] = s;
        rmax[r] = fmaxf(rmax[r], s);
      }
    }
    for(int m=1;m<16;m<<=1)
      for(int r=0;r<4;r++) rmax[r] = fmaxf(rmax[r], __shfl_xor(rmax[r], m, 64));
    float rsum[4] = {0.f,0.f,0.f,0.f};
    for(int nt=0;nt<16;nt++)
      for(int r=0;r<4;r++){ float p = __expf(sAcc[nt][r]-rmax[r]); sAcc[nt][r]=p; rsum[r]+=p; }
    for(int m=1;m<16;m<<=1)
      for(int r=0;r<4;r++) rsum[r] += __shfl_xor(rsum[r], m, 64);
    for(int nt=0;nt<16;nt++)
      for(int r=0;r<4;r++) P[(q4*4+r)*264 + nt*16 + l16] = f2bf(sAcc[nt][r]);
    __syncthreads();
    f32x4 oAcc[4];
    for(int dt=0;dt<4;dt++) oAcc[dt] = (f32x4){0.f,0.f,0.f,0.f};
    for(int kc=0;kc<8;kc++){
      bf16x8 ap = *(const bf16x8*)(P + l16*264 + kc*32 + q4*8);
      for(int dt=0; dt<4; dt++){
        const u16* vrow = vtg + ((size_t)(bh*64) + dt*16 + l16)*256 + kc*32 + q4*8;
        bf16x8 bv = *(const bf16x8*)(vrow);
        oAcc[dt] = MFMA16(ap, bv, oAcc[dt]);
      }
    }
    float rinv[4]; for(int r=0;r<4;r++) rinv[r] = 1.f/rsum[r];
    for(int dt=0;dt<4;dt++)
      for(int r=0;r<4;r++){
        int row = q0 + q4*4 + r, col = h*64 + dt*16 + l16;
        o[((size_t)(b*4096)+row)*128 + col] = f2bf(oAcc[dt][r]*rinv[r]);
      }
    __syncthreads();
  }
}

// ---------- token2map for h (512 ch): one cell per 128-thr block, 4-point pipelined ----------
__global__ __launch_bounds__(128) void k_hmap(const u16* __restrict__ hsrc, const int* __restrict__ iagg,
    const int* __restrict__ offs_all, const int* __restrict__ list_all, u16* __restrict__ hmap){
  int b = blockIdx.x >> 12, cell = blockIdx.x & 4095;
  int c0 = threadIdx.x*4;
  int st = offs_all[b*4097+cell], en = offs_all[b*4097+cell+1];
  float a0=0.f,a1=0.f,a2=0.f,a3=0.f;
  for(int p=st;p<en;p+=4){
    int idx[4]; float vm[4];
    #pragma unroll
    for(int j=0;j<4;j++){
      int pj = (p+j < en) ? p+j : en-1;
      vm[j] = (p+j < en) ? 1.f : 0.f;
      idx[j] = list_all[(b<<14)+pj];
    }
    int src[4];
    #pragma unroll
    for(int j=0;j<4;j++) src[j] = iagg[(b<<14)+idx[j]];
    uint2 u[4];
    #pragma unroll
    for(int j=0;j<4;j++) u[j] = *(const uint2*)(hsrc + ((size_t)(b<<12)+src[j])*512 + c0);
    #pragma unroll
    for(int j=0;j<4;j++){
      a0 += vm[j]*bf2f(u[j].x & 0xffffu); a1 += vm[j]*bf2f(u[j].x >> 16);
      a2 += vm[j]*bf2f(u[j].y & 0xffffu); a3 += vm[j]*bf2f(u[j].y >> 16);
    }
  }
  float inv = 1.f/fmaxf((float)(en-st), 1.f);
  uint2 o; o.x = pk2(a0*inv, a1*inv); o.y = pk2(a2*inv, a3*inv);
  *(uint2*)(hmap + ((size_t)(b<<12)+cell)*512 + c0) = o;
}

// ---------- 3x3 SAME depthwise conv + bias: 4 x-positions x 4 channels per thread ----------
__global__ __launch_bounds__(256) void k_dw(const u16* __restrict__ hmap, const float* __restrict__ dww,
    const float* __restrict__ dwb, u16* __restrict__ outm){
  int g = blockIdx.x*256 + threadIdx.x;   // 1,048,576 threads
  int cq = g & 127;
  int xg = (g>>7) & 15;
  int yy = (g>>11) & 63;
  int b  = g >> 17;
  int c0 = cq*4;
  int x0 = xg*4;
  float4 bb = *(const float4*)(dwb + c0);
  float acc[4][4];
  for(int xo=0;xo<4;xo++){ acc[xo][0]=bb.x; acc[xo][1]=bb.y; acc[xo][2]=bb.z; acc[xo][3]=bb.w; }
  for(int r=0;r<3;r++){
    int ys = yy + r - 1;
    if(ys < 0 || ys > 63) continue;            // zero padding rows
    const u16* rp = hmap + ((size_t)((b<<12) + ys*64))*512;
    float col[6][4];
    for(int cc=0;cc<6;cc++){
      int xx = x0 + cc - 1;
      uint2 u = make_uint2(0u,0u);
      if(xx >= 0 && xx <= 63) u = *(const uint2*)(rp + (size_t)xx*512 + c0);
      col[cc][0]=bf2f(u.x&0xffffu); col[cc][1]=bf2f(u.x>>16);
      col[cc][2]=bf2f(u.y&0xffffu); col[cc][3]=bf2f(u.y>>16);
    }
    for(int s=0;s<3;s++){
      float4 wv = *(const float4*)(dww + (r*3+s)*512 + c0);
      for(int xo=0;xo<4;xo++){
        acc[xo][0] += wv.x*col[xo+s][0];
        acc[xo][1] += wv.y*col[xo+s][1];
        acc[xo][2] += wv.z*col[xo+s][2];
        acc[xo][3] += wv.w*col[xo+s][3];
      }
    }
  }
  for(int xo=0;xo<4;xo++){
    int pos = (b<<12) + yy*64 + x0 + xo;
    uint2 o; o.x = pk2(acc[xo][0],acc[xo][1]); o.y = pk2(acc[xo][2],acc[xo][3]);
    *(uint2*)(outm + (size_t)pos*512 + c0) = o;
  }
}

// ---------- map2token + dwskip + GELU: one token per 128-thr block, 4-point pipelined ----------
__global__ __launch_bounds__(128) void k_m2t(const u16* __restrict__ hdw, const u16* __restrict__ hbuf,
    const float* __restrict__ aggw, const int* __restrict__ idx_hw, const int* __restrict__ offs_all,
    const int* __restrict__ list_all, const float* __restrict__ dwskip, u16* __restrict__ ht){
  int b = blockIdx.x >> 12, tok = blockIdx.x & 4095;
  int c0 = threadIdx.x*4;
  int st = offs_all[(8+b)*4097+tok], en = offs_all[(8+b)*4097+tok+1];
  float n0=0.f,n1=0.f,n2=0.f,n3=0.f,den=0.f;
  for(int p=st;p<en;p+=4){
    int idx[4]; float vm[4];
    #pragma unroll
    for(int j=0;j<4;j++){
      int pj = (p+j < en) ? p+j : en-1;
      vm[j] = (p+j < en) ? 1.f : 0.f;
      idx[j] = list_all[((8+b)<<14)+pj];
    }
    float w[4]; int cell[4];
    #pragma unroll
    for(int j=0;j<4;j++){
      w[j] = vm[j]*aggw[(b<<14)+idx[j]];
      cell[j] = idx_hw[(b<<14)+idx[j]];
    }
    uint2 u[4];
    #pragma unroll
    for(int j=0;j<4;j++) u[j] = *(const uint2*)(hdw + ((size_t)(b<<12)+cell[j])*512 + c0);
    #pragma unroll
    for(int j=0;j<4;j++){
      n0 += w[j]*bf2f(u[j].x & 0xffffu); n1 += w[j]*bf2f(u[j].x >> 16);
      n2 += w[j]*bf2f(u[j].y & 0xffffu); n3 += w[j]*bf2f(u[j].y >> 16);
      den += w[j];
    }
  }
  float inv = 1.f/fmaxf(den, 1e-6f);
  uint2 hu = *(const uint2*)(hbuf + ((size_t)(b<<12)+tok)*512 + c0);
  float4 sk = *(const float4*)(dwskip + c0);
  float v0 = geluf(n0*inv + bf2f(hu.x&0xffffu)*sk.x);
  float v1 = geluf(n1*inv + bf2f(hu.x>>16)   *sk.y);
  float v2 = geluf(n2*inv + bf2f(hu.y&0xffffu)*sk.z);
  float v3 = geluf(n3*inv + bf2f(hu.y>>16)   *sk.w);
  uint2 o; o.x=pk2(v0,v1); o.y=pk2(v2,v3);
  *(uint2*)(ht + ((size_t)(b<<12)+tok)*512 + c0) = o;
}

extern "C" void kernel_launch(void* const* d_in, const int* in_sizes, int n_in,
                              void* d_out, int out_size, void* d_ws, size_t ws_size,
                              hipStream_t stream){
  (void)in_sizes; (void)n_in; (void)out_size; (void)ws_size;
  const float* x     = (const float*)d_in[0];
  const float* loc   = (const float*)d_in[1];
  const int*   iagg  = (const int*)d_in[2];
  const float* aggw  = (const float*)d_in[3];
  const float* xsrc  = (const float*)d_in[4];
  const int*   iaggs = (const int*)d_in[5];
  const float* confs = (const float*)d_in[6];
  const float* ln1g  = (const float*)d_in[7];
  const float* ln1b  = (const float*)d_in[8];
  const float* ln2g  = (const float*)d_in[9];
  const float* ln2b  = (const float*)d_in[10];
  const float* wq    = (const float*)d_in[11];
  const float* wkv   = (const float*)d_in[12];
  const float* wproj = (const float*)d_in[13];
  const float* bproj = (const float*)d_in[14];
  const float* srw   = (const float*)d_in[15];
  const float* srb   = (const float*)d_in[16];
  const float* srng  = (const float*)d_in[17];
  const float* srnb  = (const float*)d_in[18];
  const float* fc1w  = (const float*)d_in[19];
  const float* fc1b  = (const float*)d_in[20];
  const float* dww   = (const float*)d_in[21];
  const float* dwb   = (const float*)d_in[22];
  const float* dwskip= (const float*)d_in[23];
  const float* fc2w  = (const float*)d_in[24];
  const float* fc2b  = (const float*)d_in[25];
  float* out = (float*)d_out;

  char* ws = (char*)d_ws;
  size_t off = 0;
  auto A = [&](size_t n)->char*{ char* p = ws + off; off = (off + n + 255) & ~(size_t)255; return p; };
  // ---- zeroed block (cnt_all + conf_p contiguous; one memset) ----
  int*   cnt_all  = (int*)A(16*4096*4);
  float* conf_p   = (float*)A(8*256*4);
  // ---- small region ----
  int*   offs_all = (int*)A(16*4097*4);
  int*   cur_all  = (int*)A(16*4096*4);
  int*   list_all = (int*)A(16*16384*4);
  int*   idx_hw   = (int*)A(8*16384*4);
  u16* wqT    = (u16*)A(128*128*2);
  u16* wkvT   = (u16*)A(256*128*2);
  u16* wprojT = (u16*)A(128*128*2);
  u16* fc1T   = (u16*)A(512*128*2);
  u16* fc2T   = (u16*)A(128*512*2);
  u16* srwT   = (u16*)A(128*2048*2);
  // ---- big regions with explicit overlays (lifetimes verified disjoint) ----
  char* R0 = A(33554432);   // 32MB: xsn (dead after k_tmap) -> hbuf (fc1 out)
  char* R1 = A(33554432);   // 32MB: hmap (dead after k_dw) -> ht (m2t out)
  char* R2 = A(33554432);   // 32MB: {attn_o, qout, xs_part, kvout, vtg, xs} -> hdw
  char* R3 = A(8388608);    //  8MB: xs_map
  char* R4 = A(16777216);   // 16MB: x1 (float, lives to end)
  u16* xsn    = (u16*)R0;  u16* hbuf = (u16*)R0;
  u16* hmap   = (u16*)R1;  u16* ht   = (u16*)R1;
  u16* attn_o = (u16*)R2;
  u16* qout   = (u16*)(R2 + 8388608);
  float* xs_part = (float*)(R2 + 16777216);
  u16* kvout  = (u16*)(R2 + 25165824);
  u16* vtg    = (u16*)(R2 + 26214400);
  u16* xs     = (u16*)(R2 + 27262976);
  u16* hdw    = (u16*)R2;
  u16* xs_map = (u16*)R3;
  float* x1   = (float*)R4;

  hipMemsetAsync(cnt_all, 0, 16*4096*4 + 8*256*4, stream);

  k_prep<<<dim3(18688), 256, 0, stream>>>(wq, wqT, wkv, wkvT, wproj, wprojT,
      fc1w, fc1T, fc2w, fc2T, srw, srwT, loc, iagg, idx_hw, cnt_all,
      xsrc, xsn, ln1g, ln1b);

  k_scan<<<dim3(16), 1024, 0, stream>>>(cnt_all, offs_all, cur_all);
  k_fill<<<dim3(512), 256, 0, stream>>>(idx_hw, iagg, cur_all, list_all);

  k_tmap<<<dim3(32768), 64, 0, stream>>>(xsn, confs, iaggs, offs_all, list_all, xs_map, conf_p);

  k_gemm_sr<<<dim3(16,4), 256, 0, stream>>>(xs_map, srwT, xs_part);
  k_ln_sr<<<dim3(256), 256, 0, stream>>>(xs_part, srb, srng, srnb, xs);

  k_gemm_ln<<<dim3(256,1), 256, 0, stream>>>(x, ln1g, ln1b, wqT, nullptr, qout, 128);
  k_gemm<<<dim3(32,2), 256, 0, stream>>>(xs, wkvT, nullptr, nullptr, kvout, nullptr, vtg, 2048, 256, 128);

  k_attn<<<dim3(512), 256, 0, stream>>>(qout, kvout, vtg, conf_p, attn_o);

  k_gemm<<<dim3(512,1), 256, 0, stream>>>(attn_o, wprojT, bproj, x, nullptr, x1, nullptr, 32768, 128, 128);
  k_gemm_ln<<<dim3(256,4), 256, 0, stream>>>(x1, ln2g, ln2b, fc1T, fc1b, hbuf, 512);

  k_hmap<<<dim3(32768), 128, 0, stream>>>(hbuf, iagg, offs_all, list_all, hmap);
  k_dw<<<dim3(4096), 256, 0, stream>>>(hmap, dww, dwb, hdw);
  k_m2t<<<dim3(32768), 128, 0, stream>>>(hdw, hbuf, aggw, idx_hw, offs_all, list_all, dwskip, ht);

  k_gemm<<<dim3(512,1), 256, 0, stream>>>(ht, fc2T, fc2b, x1, nullptr, out, nullptr, 32768, 128, 512);
}